// Round 2
// baseline (26017.255 us; speedup 1.0000x reference)
//
#include <hip/hip_runtime.h>
#include <hip/hip_bf16.h>
#include <math.h>

#define DEPTH   6
#define DIM     200
#define HEADS   10
#define DH      20
#define NBF     59
#define FFD     800
#define DMODEL  512
#define NSEQ    64
#define SEQ     2048
#define NTOK    (NSEQ*SEQ)   // 131072
#define NCHUNK  4
#define CHROWS  (NTOK/NCHUNK)

typedef __hip_bfloat16 bf16;

constexpr float SCALE = 0.4728708045015879f;   // 20^-0.25
constexpr float RATIO = 0.1301889109808239f;   // 59^-0.5
constexpr float KEPS  = 1e-4f;

__device__ __forceinline__ float gelu_f(float x) {
    return 0.5f * x * (1.f + erff(x * 0.70710678118654752f));
}
__device__ __forceinline__ float b2f(bf16 v) { return __bfloat162float(v); }
__device__ __forceinline__ bf16 f2b(float v) { return __float2bfloat16(v); }

// ---------------- sentinel (workspace too small diagnostic) ----------------
__global__ void sentinel_kernel(float* out) {
    if (threadIdx.x == 0) out[0] = 123456.0f;
}

// ---------------- embedding: tokens are 1 (x<=0) or 5 (x>0) ----------------
__global__ __launch_bounds__(256) void embed_kernel(const float* __restrict__ x,
        const float* __restrict__ emb, bf16* __restrict__ x1, bf16* __restrict__ x2) {
    size_t idx = (size_t)blockIdx.x * 256 + threadIdx.x;  // over NTOK*DIM
    if (idx >= (size_t)NTOK * DIM) return;
    size_t t = idx / DIM; int c = (int)(idx % DIM);
    int row = (x[t] > 0.f) ? 5 : 1;
    bf16 e = f2b(emb[row * DIM + c]);
    x1[idx] = e;
    x2[idx] = e;
}

// ---------------- LN stats (one wave per token row of 200) ----------------
__global__ __launch_bounds__(256) void lnstats_kernel(const bf16* __restrict__ in,
        float* __restrict__ mu_o, float* __restrict__ rstd_o) {
    int lane = threadIdx.x & 63;
    size_t t = (size_t)blockIdx.x * 4 + (threadIdx.x >> 6);
    const bf16* row = in + t * DIM;
    float v0 = b2f(row[lane]), v1 = b2f(row[lane + 64]), v2 = b2f(row[lane + 128]);
    float v3 = (lane < 8) ? b2f(row[lane + 192]) : 0.f;
    float s = v0 + v1 + v2 + v3, qq = v0*v0 + v1*v1 + v2*v2 + v3*v3;
    #pragma unroll
    for (int o = 32; o > 0; o >>= 1) { s += __shfl_xor(s, o); qq += __shfl_xor(qq, o); }
    if (lane == 0) {
        float mu = s * (1.f / DIM);
        mu_o[t] = mu;
        rstd_o[t] = rsqrtf(qq * (1.f / DIM) - mu * mu + 1e-5f);
    }
}

__global__ __launch_bounds__(256) void finalln_kernel(const bf16* __restrict__ in1,
        const bf16* __restrict__ in2, const float* __restrict__ g,
        const float* __restrict__ b, bf16* __restrict__ out) {
    int lane = threadIdx.x & 63;
    size_t t = (size_t)blockIdx.x * 4 + (threadIdx.x >> 6);
    const bf16* r1 = in1 + t * DIM;
    const bf16* r2 = in2 + t * DIM;
    float v0 = 0.5f * (b2f(r1[lane])       + b2f(r2[lane]));
    float v1 = 0.5f * (b2f(r1[lane + 64])  + b2f(r2[lane + 64]));
    float v2 = 0.5f * (b2f(r1[lane + 128]) + b2f(r2[lane + 128]));
    float v3 = (lane < 8) ? 0.5f * (b2f(r1[lane + 192]) + b2f(r2[lane + 192])) : 0.f;
    float s = v0 + v1 + v2 + v3, qq = v0*v0 + v1*v1 + v2*v2 + v3*v3;
    #pragma unroll
    for (int o = 32; o > 0; o >>= 1) { s += __shfl_xor(s, o); qq += __shfl_xor(qq, o); }
    float mu = s * (1.f / DIM);
    float rstd = rsqrtf(qq * (1.f / DIM) - mu * mu + 1e-5f);
    bf16* orow = out + t * DIM;
    orow[lane]       = f2b((v0 - mu) * rstd * g[lane]       + b[lane]);
    orow[lane + 64]  = f2b((v1 - mu) * rstd * g[lane + 64]  + b[lane + 64]);
    orow[lane + 128] = f2b((v2 - mu) * rstd * g[lane + 128] + b[lane + 128]);
    if (lane < 8) orow[lane + 192] = f2b((v3 - mu) * rstd * g[lane + 192] + b[lane + 192]);
}

// ------- tiled GEMM: C = epi(LN?(A) @ B + bias); A,C bf16; B,bias f32 -------
// EPI: 0 = store, 1 = C += (residual add), 2 = gelu then store
// LNA: layernorm A rows on load (precomputed mu/rstd per row, g/b over K)
template<int EPI, bool LNA>
__global__ __launch_bounds__(256) void gemm_k(
        const bf16* __restrict__ A, const float* __restrict__ B,
        const float* __restrict__ bias, bf16* __restrict__ C,
        int M, int N, int K,
        const float* __restrict__ mu, const float* __restrict__ rstd,
        const float* __restrict__ lng, const float* __restrict__ lnb) {
    constexpr int BM = 64, BN = 64, BK = 16;
    __shared__ float As[BK][BM + 4];
    __shared__ float Bs[BK][BN + 4];
    int bm = blockIdx.x * BM;
    int bn = blockIdx.y * BN;
    int tx = threadIdx.x % 16, ty = threadIdx.x / 16;
    float acc[4][4] = {};
    for (int k0 = 0; k0 < K; k0 += BK) {
        #pragma unroll
        for (int i = 0; i < 4; ++i) {
            int e = threadIdx.x + i * 256;
            int mm = e / BK, kk = e % BK;
            int row = bm + mm, kc = k0 + kk;
            float a = 0.f;
            if (kc < K) {
                a = b2f(A[(size_t)row * K + kc]);
                if (LNA) a = (a - mu[row]) * rstd[row] * lng[kc] + lnb[kc];
            }
            As[kk][mm] = a;
        }
        #pragma unroll
        for (int i = 0; i < 4; ++i) {
            int e = threadIdx.x + i * 256;
            int kk = e / BN, nn = e % BN;
            int kc = k0 + kk, col = bn + nn;
            Bs[kk][nn] = (kc < K && col < N) ? B[(size_t)kc * N + col] : 0.f;
        }
        __syncthreads();
        #pragma unroll
        for (int kk = 0; kk < BK; ++kk) {
            float ar[4], br[4];
            #pragma unroll
            for (int i = 0; i < 4; ++i) ar[i] = As[kk][ty * 4 + i];
            #pragma unroll
            for (int j = 0; j < 4; ++j) br[j] = Bs[kk][tx * 4 + j];
            #pragma unroll
            for (int i = 0; i < 4; ++i)
                #pragma unroll
                for (int j = 0; j < 4; ++j) acc[i][j] += ar[i] * br[j];
        }
        __syncthreads();
    }
    #pragma unroll
    for (int i = 0; i < 4; ++i) {
        int row = bm + ty * 4 + i;
        #pragma unroll
        for (int j = 0; j < 4; ++j) {
            int col = bn + tx * 4 + j;
            if (col < N) {
                float v = acc[i][j] + bias[col];
                size_t idx = (size_t)row * N + col;
                if (EPI == 1) v += b2f(C[idx]);
                if (EPI == 2) v = gelu_f(v);
                C[idx] = f2b(v);
            }
        }
    }
}

// ---------------- FAVOR+ stages ----------------
__global__ void initkmax_kernel(unsigned* kmax_u) {
    if (threadIdx.x == 0) *kmax_u = 0x00800000u;   // enc(-FLT_MAX)
}

__global__ __launch_bounds__(256) void kmax_kernel(const bf16* __restrict__ k,
        const float* __restrict__ proj, unsigned* __restrict__ kmax_u) {
    __shared__ float projs[NBF * DH];
    __shared__ float wmax[4];
    for (int i = threadIdx.x; i < NBF * DH; i += 256) projs[i] = proj[i];
    __syncthreads();
    float mx = -3.4e38f;
    int total = NTOK * HEADS;
    for (int u = blockIdx.x * 256 + threadIdx.x; u < total; u += gridDim.x * 256) {
        int t = u / HEADS, h = u % HEADS;
        const bf16* kr = k + (size_t)t * DIM + h * DH;
        float kn[DH];
        #pragma unroll
        for (int d = 0; d < DH; ++d) kn[d] = b2f(kr[d]) * SCALE;
        for (int m = 0; m < NBF; ++m) {
            float dot = 0.f;
            #pragma unroll
            for (int d = 0; d < DH; ++d) dot += kn[d] * projs[m * DH + d];
            mx = fmaxf(mx, dot);
        }
    }
    #pragma unroll
    for (int o = 32; o > 0; o >>= 1) mx = fmaxf(mx, __shfl_xor(mx, o));
    if ((threadIdx.x & 63) == 0) wmax[threadIdx.x >> 6] = mx;
    __syncthreads();
    if (threadIdx.x == 0) {
        float m2 = fmaxf(fmaxf(wmax[0], wmax[1]), fmaxf(wmax[2], wmax[3]));
        unsigned u = __float_as_uint(m2);
        u = (u & 0x80000000u) ? ~u : (u | 0x80000000u);
        atomicMax(kmax_u, u);
    }
}

// per-(n,h) block: ctx[d*NBF+m] = sum_s kp[s,m]*v[s,d]; ksum[m] = sum_s kp[s,m]
__global__ __launch_bounds__(256) void kvctx_kernel(const bf16* __restrict__ k,
        const bf16* __restrict__ v, const float* __restrict__ proj,
        const unsigned* __restrict__ kmax_u,
        float* __restrict__ ctx, float* __restrict__ ksum) {
    __shared__ float projs[NBF * DH];
    __shared__ float ks[64][DH];
    __shared__ float vs[64][DH];
    __shared__ float kps[64][NBF + 1];
    __shared__ float diag[64];
    int n = blockIdx.x / HEADS, h = blockIdx.x % HEADS;
    for (int i = threadIdx.x; i < NBF * DH; i += 256) projs[i] = proj[i];
    unsigned su = *kmax_u;
    float kmax = (su & 0x80000000u) ? __uint_as_float(su & 0x7FFFFFFFu)
                                    : __uint_as_float(~su);
    float acc[5] = {0.f, 0.f, 0.f, 0.f, 0.f};
    float ksr = 0.f;
    for (int c = 0; c < SEQ / 64; ++c) {
        int s0 = c * 64;
        __syncthreads();   // protect previous iteration's kps/vs reads
        for (int i = threadIdx.x; i < 64 * DH; i += 256) {
            int s = i / DH, d = i % DH;
            size_t base = ((size_t)(n * SEQ + s0 + s)) * DIM + h * DH + d;
            ks[s][d] = b2f(k[base]) * SCALE;
            vs[s][d] = b2f(v[base]);
        }
        __syncthreads();
        if (threadIdx.x < 64) {
            float dg = 0.f;
            #pragma unroll
            for (int d = 0; d < DH; ++d) { float t = ks[threadIdx.x][d]; dg += t * t; }
            diag[threadIdx.x] = 0.5f * dg;
        }
        __syncthreads();
        for (int e = threadIdx.x; e < 64 * NBF; e += 256) {
            int s = e / NBF, m = e % NBF;
            float dot = 0.f;
            #pragma unroll
            for (int d = 0; d < DH; ++d) dot += ks[s][d] * projs[m * DH + d];
            kps[s][m] = RATIO * (__expf(dot - diag[s] - kmax) + KEPS);
        }
        __syncthreads();
        if (threadIdx.x < NBF) {
            float ss = 0.f;
            for (int s = 0; s < 64; ++s) ss += kps[s][threadIdx.x];
            ksr += ss;
        }
        #pragma unroll
        for (int r = 0; r < 5; ++r) {
            int p = threadIdx.x + r * 256;
            if (p < DH * NBF) {
                int d = p / NBF, m = p % NBF;
                float a = acc[r];
                for (int s = 0; s < 64; ++s) a += kps[s][m] * vs[s][d];
                acc[r] = a;
            }
        }
    }
    #pragma unroll
    for (int r = 0; r < 5; ++r) {
        int p = threadIdx.x + r * 256;
        if (p < DH * NBF) ctx[(size_t)blockIdx.x * (DH * NBF) + p] = acc[r];
    }
    if (threadIdx.x < NBF) ksum[blockIdx.x * NBF + threadIdx.x] = ksr;
}

// per-(n,h,s): qp row, d_inv, output = qp@ctx * d_inv
__global__ __launch_bounds__(256) void qattn_kernel(const bf16* __restrict__ q,
        const float* __restrict__ proj, const float* __restrict__ ctx,
        const float* __restrict__ ksum, bf16* __restrict__ ao) {
    __shared__ float projs[NBF * DH];
    __shared__ float ctxs[DH * NBF];
    __shared__ float ksums[NBF];
    int b = blockIdx.x;
    int n = b / (HEADS * 8);
    int h = (b / 8) % HEADS;
    int sc = b % 8;
    int nh = n * HEADS + h;
    for (int i = threadIdx.x; i < NBF * DH; i += 256) {
        projs[i] = proj[i];
        ctxs[i] = ctx[(size_t)nh * NBF * DH + i];
    }
    if (threadIdx.x < NBF) ksums[threadIdx.x] = ksum[nh * NBF + threadIdx.x];
    __syncthreads();
    int s = sc * 256 + threadIdx.x;
    size_t tok = (size_t)n * SEQ + s;
    const bf16* qr = q + tok * DIM + h * DH;
    float qn[DH];
    float dg = 0.f;
    #pragma unroll
    for (int d = 0; d < DH; ++d) { qn[d] = b2f(qr[d]) * SCALE; dg += qn[d] * qn[d]; }
    dg *= 0.5f;
    float mx = -3.4e38f;
    for (int m = 0; m < NBF; ++m) {
        float dot = 0.f;
        #pragma unroll
        for (int d = 0; d < DH; ++d) dot += qn[d] * projs[m * DH + d];
        mx = fmaxf(mx, dot);
    }
    float den = 0.f;
    float out[DH];
    #pragma unroll
    for (int d = 0; d < DH; ++d) out[d] = 0.f;
    for (int m = 0; m < NBF; ++m) {
        float dot = 0.f;
        #pragma unroll
        for (int d = 0; d < DH; ++d) dot += qn[d] * projs[m * DH + d];
        float qp = RATIO * (__expf(dot - dg - mx) + KEPS);
        den += qp * ksums[m];
        #pragma unroll
        for (int d = 0; d < DH; ++d) out[d] += qp * ctxs[d * NBF + m];
    }
    float dinv = 1.f / den;
    bf16* orow = ao + tok * DIM + h * DH;
    #pragma unroll
    for (int d = 0; d < DH; ++d) orow[d] = f2b(out[d] * dinv);
}

// ---------------- pooling ----------------
__global__ __launch_bounds__(256) void pool1_kernel(const bf16* __restrict__ hn,
        float* __restrict__ partial) {
    int n = blockIdx.x / 16, c = blockIdx.x % 16;
    int d = threadIdx.x;
    if (d >= DIM) return;
    float acc = 0.f;
    const bf16* base = hn + ((size_t)n * SEQ + c * 128) * DIM + d;
    for (int s = 0; s < 128; ++s) acc += b2f(base[(size_t)s * DIM]);
    partial[(size_t)blockIdx.x * DIM + d] = acc;
}

__global__ __launch_bounds__(256) void pool2_kernel(const float* __restrict__ partial,
        float* __restrict__ pooled) {
    int n = blockIdx.x, d = threadIdx.x;
    if (d >= DIM) return;
    float acc = 0.f;
    for (int c = 0; c < 16; ++c) acc += partial[(size_t)(n * 16 + c) * DIM + d];
    pooled[n * DIM + d] = acc * (1.f / SEQ);
}

// ---------------- final projection: out[n][j] = pooled[n]·pw[:,j] + pb[j] ----
__global__ __launch_bounds__(512) void finalproj_kernel(const float* __restrict__ pooled,
        const float* __restrict__ pw, const float* __restrict__ pb,
        float* __restrict__ out) {
    __shared__ float ps[DIM];
    int n = blockIdx.x;
    for (int i = threadIdx.x; i < DIM; i += 512) ps[i] = pooled[n * DIM + i];
    __syncthreads();
    int j = threadIdx.x;
    float acc = pb[j];
    for (int d = 0; d < DIM; ++d) acc += ps[d] * pw[d * DMODEL + j];
    out[n * DMODEL + j] = acc;
}

// ---------------- host launch ----------------
extern "C" void kernel_launch(void* const* d_in, const int* in_sizes, int n_in,
                              void* d_out, int out_size, void* d_ws, size_t ws_size,
                              hipStream_t stream) {
    (void)in_sizes; (void)n_in; (void)out_size;
    const float* x    = (const float*)d_in[0];
    const float* emb  = (const float*)d_in[1];
    const float* ln1g = (const float*)d_in[2];
    const float* ln1b = (const float*)d_in[3];
    const float* wq   = (const float*)d_in[4];
    const float* bq   = (const float*)d_in[5];
    const float* wk   = (const float*)d_in[6];
    const float* bk   = (const float*)d_in[7];
    const float* wv   = (const float*)d_in[8];
    const float* bv   = (const float*)d_in[9];
    const float* proj = (const float*)d_in[10];
    const float* wo   = (const float*)d_in[11];
    const float* bo   = (const float*)d_in[12];
    const float* ln2g = (const float*)d_in[13];
    const float* ln2b = (const float*)d_in[14];
    const float* ffw1 = (const float*)d_in[15];
    const float* ffb1 = (const float*)d_in[16];
    const float* ffw2 = (const float*)d_in[17];
    const float* ffb2 = (const float*)d_in[18];
    const float* lnfg = (const float*)d_in[19];
    const float* lnfb = (const float*)d_in[20];
    const float* pw   = (const float*)d_in[21];
    const float* pb   = (const float*)d_in[22];
    float* out = (float*)d_out;

    const size_t A = (size_t)NTOK * DIM;              // 26,214,400 elems
    const size_t bfBytes = A * sizeof(bf16);          // 52,428,800 B
    bf16* x1 = (bf16*)d_ws;
    bf16* x2 = x1 + A;
    bf16* b3 = x2 + A;    // k -> q -> FF hidden chunk -> final LN out
    bf16* b4 = b3 + A;    // v -> attn out
    float* F = (float*)((char*)d_ws + 4 * bfBytes);
    float* ctx    = F;                                       // 640*1180
    float* ksum   = ctx + (size_t)NSEQ * HEADS * DH * NBF;   // 640*59
    float* muB    = ksum + (size_t)NSEQ * HEADS * NBF;       // NTOK
    float* rstdB  = muB + NTOK;                              // NTOK
    float* partial= rstdB + NTOK;                            // 64*16*200
    float* pooled = partial + (size_t)NSEQ * 16 * DIM;       // 64*200
    unsigned* kmaxu = (unsigned*)(pooled + (size_t)NSEQ * DIM);

    size_t needF = (size_t)NSEQ * HEADS * DH * NBF + (size_t)NSEQ * HEADS * NBF
                 + 2 * (size_t)NTOK + (size_t)NSEQ * 16 * DIM + (size_t)NSEQ * DIM + 4;
    size_t need = 4 * bfBytes + needF * sizeof(float);   // ~216 MB
    if (ws_size < need) {
        sentinel_kernel<<<1, 64, 0, stream>>>(out);
        return;
    }

    // embedding -> x1, x2
    embed_kernel<<<(int)(((size_t)NTOK * DIM + 255) / 256), 256, 0, stream>>>(x, emb, x1, x2);

    dim3 gqkv(NTOK / 64, (DIM + 63) / 64);
    for (int l = 0; l < DEPTH; ++l) {
        const float* wq_l = wq + (size_t)l * DIM * DIM;
        const float* wk_l = wk + (size_t)l * DIM * DIM;
        const float* wv_l = wv + (size_t)l * DIM * DIM;
        const float* wo_l = wo + (size_t)l * DIM * DIM;
        const float* pj_l = proj + (size_t)l * NBF * DH;
        const float* w1_l = ffw1 + (size_t)l * DIM * FFD;
        const float* w2_l = ffw2 + (size_t)l * FFD * DIM;

        // LN1 stats of x2; QKV GEMMs fuse the layernorm on A-load
        lnstats_kernel<<<NTOK / 4, 256, 0, stream>>>(x2, muB, rstdB);

        // b3 = k
        gemm_k<0, true><<<gqkv, 256, 0, stream>>>(x2, wk_l, bk + l * DIM, b3,
                NTOK, DIM, DIM, muB, rstdB, ln1g + l * DIM, ln1b + l * DIM);
        initkmax_kernel<<<1, 64, 0, stream>>>(kmaxu);
        kmax_kernel<<<2048, 256, 0, stream>>>(b3, pj_l, kmaxu);
        // b4 = v
        gemm_k<0, true><<<gqkv, 256, 0, stream>>>(x2, wv_l, bv + l * DIM, b4,
                NTOK, DIM, DIM, muB, rstdB, ln1g + l * DIM, ln1b + l * DIM);
        kvctx_kernel<<<NSEQ * HEADS, 256, 0, stream>>>(b3, b4, pj_l, kmaxu, ctx, ksum);
        // b3 = q (k dead)
        gemm_k<0, true><<<gqkv, 256, 0, stream>>>(x2, wq_l, bq + l * DIM, b3,
                NTOK, DIM, DIM, muB, rstdB, ln1g + l * DIM, ln1b + l * DIM);
        // b4 = attn out (v dead)
        qattn_kernel<<<NSEQ * HEADS * 8, 256, 0, stream>>>(b3, pj_l, ctx, ksum, b4);
        // x1 += b4 @ wo + bo
        gemm_k<1, false><<<gqkv, 256, 0, stream>>>(b4, wo_l, bo + l * DIM, x1,
                NTOK, DIM, DIM, nullptr, nullptr, nullptr, nullptr);

        // FF: LN2 fused on load; chunked so hidden (rows x 800) fits in b3
        lnstats_kernel<<<NTOK / 4, 256, 0, stream>>>(x1, muB, rstdB);
        for (int c = 0; c < NCHUNK; ++c) {
            const bf16* x1c = x1 + (size_t)c * CHROWS * DIM;
            bf16* x2c = x2 + (size_t)c * CHROWS * DIM;
            dim3 gff1(CHROWS / 64, (FFD + 63) / 64);
            gemm_k<2, true><<<gff1, 256, 0, stream>>>(x1c, w1_l, ffb1 + l * FFD, b3,
                    CHROWS, FFD, DIM, muB + (size_t)c * CHROWS, rstdB + (size_t)c * CHROWS,
                    ln2g + l * DIM, ln2b + l * DIM);
            dim3 gff2(CHROWS / 64, (DIM + 63) / 64);
            gemm_k<1, false><<<gff2, 256, 0, stream>>>(b3, w2_l, ffb2 + l * DIM, x2c,
                    CHROWS, DIM, FFD, nullptr, nullptr, nullptr, nullptr);
        }
    }

    // h = LN_f(0.5*(x1+x2)) -> b3 ; pooled = mean_s ; out = pooled@pw + pb
    finalln_kernel<<<NTOK / 4, 256, 0, stream>>>(x1, x2, lnfg, lnfb, b3);
    pool1_kernel<<<NSEQ * 16, 256, 0, stream>>>(b3, partial);
    pool2_kernel<<<NSEQ, 256, 0, stream>>>(partial, pooled);
    finalproj_kernel<<<NSEQ, 512, 0, stream>>>(pooled, pw, pb, out);
}

// Round 3
// 9167.349 us; speedup vs baseline: 2.8380x; 2.8380x over previous
//
#include <hip/hip_runtime.h>
#include <hip/hip_bf16.h>
#include <math.h>

#define DEPTH   6
#define DIM     200
#define HEADS   10
#define DH      20
#define NBF     59
#define FFD     800
#define DMODEL  512
#define NSEQ    64
#define SEQ     2048
#define NTOK    (NSEQ*SEQ)   // 131072
#define NCHUNK  4
#define CHROWS  (NTOK/NCHUNK)
#define KPAD    224          // ceil(200/32)*32
#define QW      (256*KPAD)   // one QKV/WO weight panel (Npad=256)
#define F1W     (896*KPAD)   // ffw1 panel (Npad=896)
#define F2W     (256*800)    // ffw2 panel (Npad=256, Kpad=800)
#define LAYERW  (4*QW + F1W + F2W)
#define WTTOT   ((size_t)DEPTH * LAYERW)
#define BUFPAD  64

typedef __hip_bfloat16 bf16;
typedef short s8v __attribute__((ext_vector_type(8)));
typedef float f4v __attribute__((ext_vector_type(4)));

constexpr float SCALE = 0.4728708045015879f;   // 20^-0.25
constexpr float RATIO = 0.1301889109808239f;   // 59^-0.5
constexpr float KEPS  = 1e-4f;

__device__ __forceinline__ float b2f(bf16 v) { return __bfloat162float(v); }
__device__ __forceinline__ bf16 f2b(float v) { return __float2bfloat16(v); }
__device__ __forceinline__ float gelu_f(float x) {
    return 0.5f * x * (1.f + erff(x * 0.70710678118654752f));
}

// ---------------- sentinel: encodes ws_size(MB) into out[0] ----------------
__global__ void sentinel_kernel(float* out, float wsmb) {
    if (threadIdx.x == 0) out[0] = wsmb;
}

__global__ void zeropad_kernel(bf16* p1, bf16* p2, bf16* p3, bf16* p4) {
    int i = threadIdx.x;
    if (i < BUFPAD) {
        bf16 z = f2b(0.f);
        p1[i] = z; p2[i] = z; p3[i] = z; p4[i] = z;
    }
}

// ------- weight prep: bf16, transposed [N][K], zero-padded panels -------
__global__ __launch_bounds__(256) void prep_w(
        const float* __restrict__ wq, const float* __restrict__ wk,
        const float* __restrict__ wv, const float* __restrict__ wo,
        const float* __restrict__ f1, const float* __restrict__ f2,
        bf16* __restrict__ WT) {
    size_t idx = (size_t)blockIdx.x * 256 + threadIdx.x;
    if (idx >= WTTOT) return;
    int lyr = (int)(idx / LAYERW);
    int r   = (int)(idx % LAYERW);
    float val = 0.f;
    if (r < 4*QW) {
        int m = r / QW, rr = r % QW;
        int n = rr / KPAD, k = rr % KPAD;
        if (n < DIM && k < DIM) {
            const float* s = (m==0) ? wq : (m==1) ? wk : (m==2) ? wv : wo;
            val = s[(size_t)lyr*DIM*DIM + (size_t)k*DIM + n];
        }
    } else if (r < 4*QW + F1W) {
        int rr = r - 4*QW;
        int n = rr / KPAD, k = rr % KPAD;
        if (n < FFD && k < DIM)
            val = f1[(size_t)lyr*DIM*FFD + (size_t)k*FFD + n];
    } else {
        int rr = r - 4*QW - F1W;
        int n = rr / 800, k = rr % 800;
        if (n < DIM)
            val = f2[(size_t)lyr*FFD*DIM + (size_t)k*DIM + n];
    }
    WT[idx] = f2b(val);
}

// ---------------- embedding: tokens are 1 (x<=0) or 5 (x>0) ----------------
__global__ __launch_bounds__(256) void embed_kernel(const float* __restrict__ x,
        const float* __restrict__ emb, bf16* __restrict__ x1, bf16* __restrict__ x2) {
    size_t idx = (size_t)blockIdx.x * 256 + threadIdx.x;
    if (idx >= (size_t)NTOK * DIM) return;
    size_t t = idx / DIM; int c = (int)(idx % DIM);
    int row = (x[t] > 0.f) ? 5 : 1;
    bf16 e = f2b(emb[row * DIM + c]);
    x1[idx] = e;
    x2[idx] = e;
}

// ---------------- LN stats (one wave per token row of 200) ----------------
__global__ __launch_bounds__(256) void lnstats_kernel(const bf16* __restrict__ in,
        float* __restrict__ mu_o, float* __restrict__ rstd_o) {
    int lane = threadIdx.x & 63;
    size_t t = (size_t)blockIdx.x * 4 + (threadIdx.x >> 6);
    const bf16* row = in + t * DIM;
    float v0 = b2f(row[lane]), v1 = b2f(row[lane + 64]), v2 = b2f(row[lane + 128]);
    float v3 = (lane < 8) ? b2f(row[lane + 192]) : 0.f;
    float s = v0 + v1 + v2 + v3, qq = v0*v0 + v1*v1 + v2*v2 + v3*v3;
    #pragma unroll
    for (int o = 32; o > 0; o >>= 1) { s += __shfl_xor(s, o); qq += __shfl_xor(qq, o); }
    if (lane == 0) {
        float mu = s * (1.f / DIM);
        mu_o[t] = mu;
        rstd_o[t] = rsqrtf(qq * (1.f / DIM) - mu * mu + 1e-5f);
    }
}

__global__ __launch_bounds__(256) void finalln_kernel(const bf16* __restrict__ in1,
        const bf16* __restrict__ in2, const float* __restrict__ g,
        const float* __restrict__ b, bf16* __restrict__ out) {
    int lane = threadIdx.x & 63;
    size_t t = (size_t)blockIdx.x * 4 + (threadIdx.x >> 6);
    const bf16* r1 = in1 + t * DIM;
    const bf16* r2 = in2 + t * DIM;
    float v0 = 0.5f * (b2f(r1[lane])       + b2f(r2[lane]));
    float v1 = 0.5f * (b2f(r1[lane + 64])  + b2f(r2[lane + 64]));
    float v2 = 0.5f * (b2f(r1[lane + 128]) + b2f(r2[lane + 128]));
    float v3 = (lane < 8) ? 0.5f * (b2f(r1[lane + 192]) + b2f(r2[lane + 192])) : 0.f;
    float s = v0 + v1 + v2 + v3, qq = v0*v0 + v1*v1 + v2*v2 + v3*v3;
    #pragma unroll
    for (int o = 32; o > 0; o >>= 1) { s += __shfl_xor(s, o); qq += __shfl_xor(qq, o); }
    float mu = s * (1.f / DIM);
    float rstd = rsqrtf(qq * (1.f / DIM) - mu * mu + 1e-5f);
    bf16* orow = out + t * DIM;
    orow[lane]       = f2b((v0 - mu) * rstd * g[lane]       + b[lane]);
    orow[lane + 64]  = f2b((v1 - mu) * rstd * g[lane + 64]  + b[lane + 64]);
    orow[lane + 128] = f2b((v2 - mu) * rstd * g[lane + 128] + b[lane + 128]);
    if (lane < 8) orow[lane + 192] = f2b((v3 - mu) * rstd * g[lane + 192] + b[lane + 192]);
}

// ---------------- MFMA GEMM: C = epi(LN?(A) @ Bt^T + bias) ----------------
// A: bf16 [M][K] row-major (stride K). Bt: bf16 [Npad][Kpad] (transposed,
// zero-padded). C: bf16 [M][N]. BM=BN=128, BK=32, 4 waves (2x2 of 64x64).
// EPI: 0 = store, 1 = C += v, 2 = gelu(v). LNA: layernorm rows of A on stage.
template<int EPI, bool LNA>
__global__ __launch_bounds__(256) void gemm_m(
        const bf16* __restrict__ A, const bf16* __restrict__ Bt,
        const float* __restrict__ bias, bf16* __restrict__ C,
        int M, int N, int K, int Kpad,
        const float* __restrict__ mu, const float* __restrict__ rstd,
        const float* __restrict__ lng, const float* __restrict__ lnb) {
    __shared__ __align__(16) short As[128 * 40];
    __shared__ __align__(16) short Bs[128 * 40];
    int bm = blockIdx.x * 128, bn = blockIdx.y * 128;
    int t = threadIdx.x, l = t & 63, w = t >> 6;
    int wr = (w >> 1) * 64, wc = (w & 1) * 64;
    int lr = l & 15, lk = (l >> 4) * 8;
    f4v zero4 = {0.f, 0.f, 0.f, 0.f};
    f4v acc[4][4];
    #pragma unroll
    for (int i = 0; i < 4; ++i)
        #pragma unroll
        for (int j = 0; j < 4; ++j) acc[i][j] = zero4;

    const short* Ash = (const short*)A;
    const short* Bsh = (const short*)Bt;
    for (int k0 = 0; k0 < Kpad; k0 += 32) {
        __syncthreads();
        #pragma unroll
        for (int i2 = 0; i2 < 2; ++i2) {
            int c = t * 2 + i2;                 // 0..511
            int row = c >> 2, ko = (c & 3) * 8;
            s8v av = *(const s8v*)(Ash + (size_t)(bm + row) * K + k0 + ko);
            if (LNA) {
                float m_ = mu[bm + row], rs_ = rstd[bm + row];
                #pragma unroll
                for (int j = 0; j < 8; ++j) {
                    int kc = k0 + ko + j; if (kc >= K) kc = K - 1;
                    float f = __uint_as_float(((unsigned)(unsigned short)av[j]) << 16);
                    f = (f - m_) * rs_ * lng[kc] + lnb[kc];
                    bf16 hb = f2b(f);
                    av[j] = *(short*)&hb;
                }
            }
            *(s8v*)&As[row * 40 + ko] = av;
            s8v bv = *(const s8v*)(Bsh + (size_t)(bn + row) * Kpad + k0 + ko);
            *(s8v*)&Bs[row * 40 + ko] = bv;
        }
        __syncthreads();
        s8v a[4], b[4];
        #pragma unroll
        for (int fi = 0; fi < 4; ++fi)
            a[fi] = *(const s8v*)&As[(wr + fi * 16 + lr) * 40 + lk];
        #pragma unroll
        for (int fj = 0; fj < 4; ++fj)
            b[fj] = *(const s8v*)&Bs[(wc + fj * 16 + lr) * 40 + lk];
        #pragma unroll
        for (int fi = 0; fi < 4; ++fi)
            #pragma unroll
            for (int fj = 0; fj < 4; ++fj)
                acc[fi][fj] = __builtin_amdgcn_mfma_f32_16x16x32_bf16(
                        a[fi], b[fj], acc[fi][fj], 0, 0, 0);
    }
    int r0 = (l >> 4) * 4;
    #pragma unroll
    for (int fi = 0; fi < 4; ++fi) {
        int row0 = bm + wr + fi * 16 + r0;
        #pragma unroll
        for (int fj = 0; fj < 4; ++fj) {
            int col = bn + wc + fj * 16 + lr;
            if (col < N) {
                float bvv = bias[col];
                #pragma unroll
                for (int r = 0; r < 4; ++r) {
                    size_t idx = (size_t)(row0 + r) * N + col;
                    float v = acc[fi][fj][r] + bvv;
                    if (EPI == 1) v += b2f(C[idx]);
                    if (EPI == 2) v = gelu_f(v);
                    C[idx] = f2b(v);
                }
            }
        }
    }
}

// ---------------- FAVOR+ stages ----------------
__global__ void initkmax_kernel(unsigned* kmax_u) {
    if (threadIdx.x == 0) *kmax_u = 0x00800000u;   // enc(-FLT_MAX)
}

__global__ __launch_bounds__(256) void kmax_kernel(const bf16* __restrict__ k,
        const float* __restrict__ proj, unsigned* __restrict__ kmax_u) {
    __shared__ float projs[NBF * DH];
    __shared__ float wmax[4];
    for (int i = threadIdx.x; i < NBF * DH; i += 256) projs[i] = proj[i];
    __syncthreads();
    float mx = -3.4e38f;
    int total = NTOK * HEADS;
    for (int u = blockIdx.x * 256 + threadIdx.x; u < total; u += gridDim.x * 256) {
        int t = u / HEADS, h = u % HEADS;
        const bf16* kr = k + (size_t)t * DIM + h * DH;
        float kn[DH];
        #pragma unroll
        for (int d = 0; d < DH; ++d) kn[d] = b2f(kr[d]) * SCALE;
        for (int m = 0; m < NBF; ++m) {
            float dot = 0.f;
            #pragma unroll
            for (int d = 0; d < DH; ++d) dot += kn[d] * projs[m * DH + d];
            mx = fmaxf(mx, dot);
        }
    }
    #pragma unroll
    for (int o = 32; o > 0; o >>= 1) mx = fmaxf(mx, __shfl_xor(mx, o));
    if ((threadIdx.x & 63) == 0) wmax[threadIdx.x >> 6] = mx;
    __syncthreads();
    if (threadIdx.x == 0) {
        float m2 = fmaxf(fmaxf(wmax[0], wmax[1]), fmaxf(wmax[2], wmax[3]));
        unsigned u = __float_as_uint(m2);
        u = (u & 0x80000000u) ? ~u : (u | 0x80000000u);
        atomicMax(kmax_u, u);
    }
}

// split-parallel kvctx: partial ctx/ksum per (n,h,split-slice)
__global__ __launch_bounds__(256) void kvctx_kernel(const bf16* __restrict__ k,
        const bf16* __restrict__ v, const float* __restrict__ proj,
        const unsigned* __restrict__ kmax_u,
        float* __restrict__ ctx_part, float* __restrict__ ksum_part, int split) {
    __shared__ float projs[NBF * DH];
    __shared__ float ks[64][DH];
    __shared__ float vs[64][DH];
    __shared__ float kps[64][NBF + 1];
    __shared__ float diag[64];
    int b = blockIdx.x;
    int sp = b % split, nh = b / split;
    int n = nh / HEADS, h = nh % HEADS;
    for (int i = threadIdx.x; i < NBF * DH; i += 256) projs[i] = proj[i];
    unsigned su = *kmax_u;
    float kmax = (su & 0x80000000u) ? __uint_as_float(su & 0x7FFFFFFFu)
                                    : __uint_as_float(~su);
    float acc[5] = {0.f, 0.f, 0.f, 0.f, 0.f};
    float ksr = 0.f;
    int cpb = 32 / split;
    for (int c = sp * cpb; c < (sp + 1) * cpb; ++c) {
        int s0 = c * 64;
        __syncthreads();
        for (int i = threadIdx.x; i < 64 * DH; i += 256) {
            int s = i / DH, d = i % DH;
            size_t base = ((size_t)(n * SEQ + s0 + s)) * DIM + h * DH + d;
            ks[s][d] = b2f(k[base]) * SCALE;
            vs[s][d] = b2f(v[base]);
        }
        __syncthreads();
        if (threadIdx.x < 64) {
            float dg = 0.f;
            #pragma unroll
            for (int d = 0; d < DH; ++d) { float tt = ks[threadIdx.x][d]; dg += tt * tt; }
            diag[threadIdx.x] = 0.5f * dg;
        }
        __syncthreads();
        for (int e = threadIdx.x; e < 64 * NBF; e += 256) {
            int s = e / NBF, m = e % NBF;
            float dot = 0.f;
            #pragma unroll
            for (int d = 0; d < DH; ++d) dot += ks[s][d] * projs[m * DH + d];
            kps[s][m] = RATIO * (__expf(dot - diag[s] - kmax) + KEPS);
        }
        __syncthreads();
        if (threadIdx.x < NBF) {
            float ss = 0.f;
            for (int s = 0; s < 64; ++s) ss += kps[s][threadIdx.x];
            ksr += ss;
        }
        #pragma unroll
        for (int r = 0; r < 5; ++r) {
            int p = threadIdx.x + r * 256;
            if (p < DH * NBF) {
                int d = p / NBF, m = p % NBF;
                float a = acc[r];
                for (int s = 0; s < 64; ++s) a += kps[s][m] * vs[s][d];
                acc[r] = a;
            }
        }
    }
    size_t ob = (size_t)(nh * split + sp);
    #pragma unroll
    for (int r = 0; r < 5; ++r) {
        int p = threadIdx.x + r * 256;
        if (p < DH * NBF) ctx_part[ob * (DH * NBF) + p] = acc[r];
    }
    if (threadIdx.x < NBF) ksum_part[ob * NBF + threadIdx.x] = ksr;
}

__global__ __launch_bounds__(256) void reduce_kernel(const float* __restrict__ ctx_part,
        const float* __restrict__ ksum_part, float* __restrict__ ctx,
        float* __restrict__ ksum, int split) {
    int i = blockIdx.x * 256 + threadIdx.x;
    if (i < NSEQ * HEADS * DH * NBF) {
        int nh = i / (DH * NBF), p = i % (DH * NBF);
        float s = 0.f;
        for (int sp = 0; sp < split; ++sp)
            s += ctx_part[(size_t)(nh * split + sp) * (DH * NBF) + p];
        ctx[i] = s;
    }
    if (i < NSEQ * HEADS * NBF) {
        int nh = i / NBF, m = i % NBF;
        float s = 0.f;
        for (int sp = 0; sp < split; ++sp)
            s += ksum_part[(size_t)(nh * split + sp) * NBF + m];
        ksum[i] = s;
    }
}

// per-(n,h,s): qp row, d_inv, output = qp@ctx * d_inv
__global__ __launch_bounds__(256) void qattn_kernel(const bf16* __restrict__ q,
        const float* __restrict__ proj, const float* __restrict__ ctx,
        const float* __restrict__ ksum, bf16* __restrict__ ao) {
    __shared__ float projs[NBF * DH];
    __shared__ float ctxs[DH * NBF];
    __shared__ float ksums[NBF];
    int b = blockIdx.x;
    int n = b / (HEADS * 8);
    int h = (b / 8) % HEADS;
    int sc = b % 8;
    int nh = n * HEADS + h;
    for (int i = threadIdx.x; i < NBF * DH; i += 256) {
        projs[i] = proj[i];
        ctxs[i] = ctx[(size_t)nh * NBF * DH + i];
    }
    if (threadIdx.x < NBF) ksums[threadIdx.x] = ksum[nh * NBF + threadIdx.x];
    __syncthreads();
    int s = sc * 256 + threadIdx.x;
    size_t tok = (size_t)n * SEQ + s;
    const bf16* qr = q + tok * DIM + h * DH;
    float qn[DH];
    float dg = 0.f;
    #pragma unroll
    for (int d = 0; d < DH; ++d) { qn[d] = b2f(qr[d]) * SCALE; dg += qn[d] * qn[d]; }
    dg *= 0.5f;
    float mx = -3.4e38f;
    for (int m = 0; m < NBF; ++m) {
        float dot = 0.f;
        #pragma unroll
        for (int d = 0; d < DH; ++d) dot += qn[d] * projs[m * DH + d];
        mx = fmaxf(mx, dot);
    }
    float den = 0.f;
    float outv[DH];
    #pragma unroll
    for (int d = 0; d < DH; ++d) outv[d] = 0.f;
    for (int m = 0; m < NBF; ++m) {
        float dot = 0.f;
        #pragma unroll
        for (int d = 0; d < DH; ++d) dot += qn[d] * projs[m * DH + d];
        float qp = RATIO * (__expf(dot - dg - mx) + KEPS);
        den += qp * ksums[m];
        #pragma unroll
        for (int d = 0; d < DH; ++d) outv[d] += qp * ctxs[d * NBF + m];
    }
    float dinv = 1.f / den;
    bf16* orow = ao + tok * DIM + h * DH;
    #pragma unroll
    for (int d = 0; d < DH; ++d) orow[d] = f2b(outv[d] * dinv);
}

// ---------------- pooling ----------------
__global__ __launch_bounds__(256) void pool1_kernel(const bf16* __restrict__ hn,
        float* __restrict__ partial) {
    int n = blockIdx.x / 16, c = blockIdx.x % 16;
    int d = threadIdx.x;
    if (d >= DIM) return;
    float acc = 0.f;
    const bf16* base = hn + ((size_t)n * SEQ + c * 128) * DIM + d;
    for (int s = 0; s < 128; ++s) acc += b2f(base[(size_t)s * DIM]);
    partial[(size_t)blockIdx.x * DIM + d] = acc;
}

__global__ __launch_bounds__(256) void pool2_kernel(const float* __restrict__ partial,
        float* __restrict__ pooled) {
    int n = blockIdx.x, d = threadIdx.x;
    if (d >= DIM) return;
    float acc = 0.f;
    for (int c = 0; c < 16; ++c) acc += partial[(size_t)(n * 16 + c) * DIM + d];
    pooled[n * DIM + d] = acc * (1.f / SEQ);
}

__global__ __launch_bounds__(512) void finalproj_kernel(const float* __restrict__ pooled,
        const float* __restrict__ pw, const float* __restrict__ pb,
        float* __restrict__ out) {
    __shared__ float ps[DIM];
    int n = blockIdx.x;
    for (int i = threadIdx.x; i < DIM; i += 512) ps[i] = pooled[n * DIM + i];
    __syncthreads();
    int j = threadIdx.x;
    float acc = pb[j];
    for (int d = 0; d < DIM; ++d) acc += ps[d] * pw[d * DMODEL + j];
    out[n * DMODEL + j] = acc;
}

// ---------------- host launch ----------------
extern "C" void kernel_launch(void* const* d_in, const int* in_sizes, int n_in,
                              void* d_out, int out_size, void* d_ws, size_t ws_size,
                              hipStream_t stream) {
    (void)in_sizes; (void)n_in; (void)out_size;
    const float* x    = (const float*)d_in[0];
    const float* emb  = (const float*)d_in[1];
    const float* ln1g = (const float*)d_in[2];
    const float* ln1b = (const float*)d_in[3];
    const float* wq   = (const float*)d_in[4];
    const float* bq   = (const float*)d_in[5];
    const float* wk   = (const float*)d_in[6];
    const float* bk   = (const float*)d_in[7];
    const float* wv   = (const float*)d_in[8];
    const float* bv   = (const float*)d_in[9];
    const float* proj = (const float*)d_in[10];
    const float* wo   = (const float*)d_in[11];
    const float* bo   = (const float*)d_in[12];
    const float* ln2g = (const float*)d_in[13];
    const float* ln2b = (const float*)d_in[14];
    const float* ffw1 = (const float*)d_in[15];
    const float* ffb1 = (const float*)d_in[16];
    const float* ffw2 = (const float*)d_in[17];
    const float* ffb2 = (const float*)d_in[18];
    const float* lnfg = (const float*)d_in[19];
    const float* lnfb = (const float*)d_in[20];
    const float* pw   = (const float*)d_in[21];
    const float* pb   = (const float*)d_in[22];
    float* out = (float*)d_out;

    const size_t A_ = (size_t)NTOK * DIM;
    bf16* x1 = (bf16*)d_ws;
    bf16* x2 = x1 + A_ + BUFPAD;
    bf16* b3 = x2 + A_ + BUFPAD;
    bf16* b4 = b3 + A_ + BUFPAD;
    bf16* WT = b4 + A_ + BUFPAD;
    float* F     = (float*)(WT + WTTOT);
    float* ctxB  = F;                                        // 640*1180
    float* ksumB = ctxB + (size_t)NSEQ * HEADS * DH * NBF;   // 640*59
    float* muB   = ksumB + (size_t)NSEQ * HEADS * NBF;       // NTOK
    float* rstdB = muB + NTOK;                               // NTOK
    unsigned* kmaxu = (unsigned*)(rstdB + NTOK);             // 16 slots
    float* parts = (float*)(kmaxu + 16);
    float* partial = muB;            // overlay: muB/rstdB dead at pooling time
    float* pooled  = muB + (size_t)NSEQ * 16 * DIM;

    size_t bfShorts = 4 * (A_ + BUFPAD) + WTTOT;
    size_t baseFloats = (size_t)NSEQ*HEADS*DH*NBF + (size_t)NSEQ*HEADS*NBF
                      + 2 * (size_t)NTOK + 16;
    size_t baseBytes = bfShorts * 2 + baseFloats * 4;
    int split = 0;
    for (int s2 = 8; s2 >= 1; s2 >>= 1) {
        if (baseBytes + (size_t)NSEQ*HEADS*s2*(DH*NBF + NBF)*4 <= ws_size) { split = s2; break; }
    }
    if (!split) {
        sentinel_kernel<<<1, 64, 0, stream>>>(out, (float)(ws_size >> 20));
        return;
    }
    float* ctx_part  = parts;
    float* ksum_part = parts + (size_t)NSEQ * HEADS * split * DH * NBF;

    prep_w<<<(int)((WTTOT + 255) / 256), 256, 0, stream>>>(wq, wk, wv, wo, ffw1, ffw2, WT);
    zeropad_kernel<<<1, 64, 0, stream>>>(x1 + A_, x2 + A_, b3 + A_, b4 + A_);
    embed_kernel<<<(int)(((size_t)NTOK * DIM + 255) / 256), 256, 0, stream>>>(x, emb, x1, x2);

    dim3 gqkv(NTOK / 128, 2);
    for (int l = 0; l < DEPTH; ++l) {
        const bf16* wqT = WT + (size_t)l * LAYERW;
        const bf16* wkT = wqT + QW;
        const bf16* wvT = wkT + QW;
        const bf16* woT = wvT + QW;
        const bf16* f1T = woT + QW;
        const bf16* f2T = f1T + F1W;
        const float* pj_l = proj + (size_t)l * NBF * DH;

        lnstats_kernel<<<NTOK / 4, 256, 0, stream>>>(x2, muB, rstdB);

        // b3 = k = LN1(x2)@wk + bk
        gemm_m<0, true><<<gqkv, 256, 0, stream>>>(x2, wkT, bk + l * DIM, b3,
                NTOK, DIM, DIM, KPAD, muB, rstdB, ln1g + l * DIM, ln1b + l * DIM);
        initkmax_kernel<<<1, 64, 0, stream>>>(kmaxu);
        kmax_kernel<<<2048, 256, 0, stream>>>(b3, pj_l, kmaxu);
        // b4 = v
        gemm_m<0, true><<<gqkv, 256, 0, stream>>>(x2, wvT, bv + l * DIM, b4,
                NTOK, DIM, DIM, KPAD, muB, rstdB, ln1g + l * DIM, ln1b + l * DIM);
        kvctx_kernel<<<NSEQ * HEADS * split, 256, 0, stream>>>(b3, b4, pj_l, kmaxu,
                ctx_part, ksum_part, split);
        reduce_kernel<<<(NSEQ * HEADS * DH * NBF + 255) / 256, 256, 0, stream>>>(
                ctx_part, ksum_part, ctxB, ksumB, split);
        // b3 = q (k dead)
        gemm_m<0, true><<<gqkv, 256, 0, stream>>>(x2, wqT, bq + l * DIM, b3,
                NTOK, DIM, DIM, KPAD, muB, rstdB, ln1g + l * DIM, ln1b + l * DIM);
        // b4 = attn out (v dead)
        qattn_kernel<<<NSEQ * HEADS * 8, 256, 0, stream>>>(b3, pj_l, ctxB, ksumB, b4);
        // x1 += b4 @ wo + bo
        gemm_m<1, false><<<gqkv, 256, 0, stream>>>(b4, woT, bo + l * DIM, x1,
                NTOK, DIM, DIM, KPAD, nullptr, nullptr, nullptr, nullptr);

        // FF: LN2 fused; hidden chunked through b3
        lnstats_kernel<<<NTOK / 4, 256, 0, stream>>>(x1, muB, rstdB);
        for (int c = 0; c < NCHUNK; ++c) {
            const bf16* x1c = x1 + (size_t)c * CHROWS * DIM;
            bf16* x2c = x2 + (size_t)c * CHROWS * DIM;
            dim3 gff1(CHROWS / 128, 7);
            gemm_m<2, true><<<gff1, 256, 0, stream>>>(x1c, f1T, ffb1 + l * FFD, b3,
                    CHROWS, FFD, DIM, KPAD, muB + (size_t)c * CHROWS,
                    rstdB + (size_t)c * CHROWS, ln2g + l * DIM, ln2b + l * DIM);
            dim3 gff2(CHROWS / 128, 2);
            gemm_m<1, false><<<gff2, 256, 0, stream>>>(b3, f2T, ffb2 + l * DIM, x2c,
                    CHROWS, DIM, FFD, FFD, nullptr, nullptr, nullptr, nullptr);
        }
    }

    finalln_kernel<<<NTOK / 4, 256, 0, stream>>>(x1, x2, lnfg, lnfb, b3);
    pool1_kernel<<<NSEQ * 16, 256, 0, stream>>>(b3, partial);
    pool2_kernel<<<NSEQ, 256, 0, stream>>>(partial, pooled);
    finalproj_kernel<<<NSEQ, 512, 0, stream>>>(pooled, pw, pb, out);
}

// Round 4
// 9112.576 us; speedup vs baseline: 2.8551x; 1.0060x over previous
//
#include <hip/hip_runtime.h>
#include <hip/hip_bf16.h>
#include <math.h>

#define DEPTH   6
#define DIM     200
#define HEADS   10
#define DH      20
#define NBF     59
#define FFD     800
#define DMODEL  512
#define NSEQ    64
#define SEQ     2048
#define NTOK    (NSEQ*SEQ)   // 131072
#define NCHUNK  2
#define CHROWS  (NTOK/NCHUNK)
#define KPAD    224          // ceil(200/32)*32
#define BUFPAD  64
#define SPLIT   4
#define P1ELEM  (896*KPAD)   // panel1 max: ffw1 [896][224]
#define P2ELEM  (256*800)    // panel2: ffw2 [256][800]

typedef __hip_bfloat16 bf16;
typedef short s8v __attribute__((ext_vector_type(8)));
typedef float f4v __attribute__((ext_vector_type(4)));

constexpr float SCALE = 0.4728708045015879f;   // 20^-0.25
constexpr float RATIO = 0.1301889109808239f;   // 59^-0.5
constexpr float KEPS  = 1e-4f;

__device__ __forceinline__ float b2f(bf16 v) { return __bfloat162float(v); }
__device__ __forceinline__ bf16 f2b(float v) { return __float2bfloat16(v); }
__device__ __forceinline__ float bfu(unsigned short u) {
    return __uint_as_float(((unsigned)u) << 16);
}
__device__ __forceinline__ unsigned short f2u(float v) {
    bf16 hb = __float2bfloat16(v);
    return *(unsigned short*)&hb;
}
__device__ __forceinline__ float gelu_f(float x) {
    return 0.5f * x * (1.f + erff(x * 0.70710678118654752f));
}

// ---------------- sentinel: encodes ws_size(MB) into out[0] ----------------
__global__ void sentinel_kernel(float* out, float wsmb) {
    if (threadIdx.x == 0) out[0] = wsmb;
}

__global__ void zeropad_kernel(bf16* p1, bf16* p2, bf16* p3, bf16* p4) {
    int i = threadIdx.x;
    if (i < BUFPAD) {
        bf16 z = f2b(0.f);
        p1[i] = z; p2[i] = z; p3[i] = z; p4[i] = z;
    }
}

// ------- panel prep: bf16, transposed [Npad][Kpad], zero-pad, opt g-fold ----
__global__ __launch_bounds__(256) void prep_panel(const float* __restrict__ W,
        const float* __restrict__ g, bf16* __restrict__ panel,
        int N, int K, int Npad, int Kpad) {
    int idx = blockIdx.x * 256 + threadIdx.x;
    if (idx >= Npad * Kpad) return;
    int n = idx / Kpad, k = idx % Kpad;
    float v = 0.f;
    if (n < N && k < K) {
        v = W[(size_t)k * N + n];
        if (g) v *= g[k];
    }
    panel[idx] = f2b(v);
}

// u[n] = sum_k g[k]W[k,n]; w[n] = sum_k b[k]W[k,n] + bias[n]
__global__ __launch_bounds__(256) void prep_uw(const float* __restrict__ W,
        const float* __restrict__ g, const float* __restrict__ bln,
        const float* __restrict__ bias, float* __restrict__ u,
        float* __restrict__ w, int N, int K) {
    int n = blockIdx.x * 256 + threadIdx.x;
    if (n >= N) return;
    float su = 0.f, sw = 0.f;
    for (int k = 0; k < K; ++k) {
        float wv = W[(size_t)k * N + n];
        su += g[k] * wv;
        sw += bln[k] * wv;
    }
    u[n] = su;
    w[n] = sw + bias[n];
}

// ---------------- embedding: tokens are 1 (x<=0) or 5 (x>0) ----------------
__global__ __launch_bounds__(256) void embed_kernel(const float* __restrict__ x,
        const float* __restrict__ emb, bf16* __restrict__ x1, bf16* __restrict__ x2) {
    int idx = blockIdx.x * 256 + threadIdx.x;      // NTOK*25
    if (idx >= NTOK * 25) return;
    int t = idx / 25, c = idx % 25;
    int row = (x[t] > 0.f) ? 5 : 1;
    const float4* e4 = (const float4*)(emb + row * DIM + c * 8);
    float4 e0 = e4[0], e1 = e4[1];
    s8v o;
    o[0] = (short)f2u(e0.x); o[1] = (short)f2u(e0.y);
    o[2] = (short)f2u(e0.z); o[3] = (short)f2u(e0.w);
    o[4] = (short)f2u(e1.x); o[5] = (short)f2u(e1.y);
    o[6] = (short)f2u(e1.z); o[7] = (short)f2u(e1.w);
    size_t off = (size_t)t * DIM + c * 8;
    *(s8v*)((short*)x1 + off) = o;
    *(s8v*)((short*)x2 + off) = o;
}

// ---------------- LN stats (one wave per token row of 200) ----------------
__global__ __launch_bounds__(256) void lnstats_kernel(const bf16* __restrict__ in,
        float* __restrict__ mu_o, float* __restrict__ rstd_o) {
    int lane = threadIdx.x & 63;
    size_t t = (size_t)blockIdx.x * 4 + (threadIdx.x >> 6);
    const ushort* row = (const ushort*)in + t * DIM;
    float v0 = 0.f, v1 = 0.f, v2 = 0.f, v3 = 0.f;
    if (lane < 50) {
        ushort4 u4 = ((const ushort4*)row)[lane];
        v0 = bfu(u4.x); v1 = bfu(u4.y); v2 = bfu(u4.z); v3 = bfu(u4.w);
    }
    float s = v0 + v1 + v2 + v3, qq = v0*v0 + v1*v1 + v2*v2 + v3*v3;
    #pragma unroll
    for (int o = 32; o > 0; o >>= 1) { s += __shfl_xor(s, o); qq += __shfl_xor(qq, o); }
    if (lane == 0) {
        float mu = s * (1.f / DIM);
        mu_o[t] = mu;
        rstd_o[t] = rsqrtf(qq * (1.f / DIM) - mu * mu + 1e-5f);
    }
}

__global__ __launch_bounds__(256) void finalln_kernel(const bf16* __restrict__ in1,
        const bf16* __restrict__ in2, const float* __restrict__ g,
        const float* __restrict__ b, bf16* __restrict__ out) {
    int lane = threadIdx.x & 63;
    size_t t = (size_t)blockIdx.x * 4 + (threadIdx.x >> 6);
    const ushort* r1 = (const ushort*)in1 + t * DIM;
    const ushort* r2 = (const ushort*)in2 + t * DIM;
    float v0 = 0.f, v1 = 0.f, v2 = 0.f, v3 = 0.f;
    if (lane < 50) {
        ushort4 a4 = ((const ushort4*)r1)[lane];
        ushort4 b4 = ((const ushort4*)r2)[lane];
        v0 = 0.5f * (bfu(a4.x) + bfu(b4.x));
        v1 = 0.5f * (bfu(a4.y) + bfu(b4.y));
        v2 = 0.5f * (bfu(a4.z) + bfu(b4.z));
        v3 = 0.5f * (bfu(a4.w) + bfu(b4.w));
    }
    float s = v0 + v1 + v2 + v3, qq = v0*v0 + v1*v1 + v2*v2 + v3*v3;
    #pragma unroll
    for (int o = 32; o > 0; o >>= 1) { s += __shfl_xor(s, o); qq += __shfl_xor(qq, o); }
    float mu = s * (1.f / DIM);
    float rstd = rsqrtf(qq * (1.f / DIM) - mu * mu + 1e-5f);
    if (lane < 50) {
        float4 g4 = ((const float4*)g)[lane];
        float4 b4f = ((const float4*)b)[lane];
        ushort4 o4;
        o4.x = f2u((v0 - mu) * rstd * g4.x + b4f.x);
        o4.y = f2u((v1 - mu) * rstd * g4.y + b4f.y);
        o4.z = f2u((v2 - mu) * rstd * g4.z + b4f.z);
        o4.w = f2u((v3 - mu) * rstd * g4.w + b4f.w);
        ((ushort4*)((ushort*)out + t * DIM))[lane] = o4;
    }
}

// ---------------- MFMA GEMM: C = epi(A @ Bt^T) + LN-epilogue ----------------
// A bf16 [M][K]; Bt bf16 [Npad][Kpad] (transposed, zero-padded, g-folded if LNE)
// LNE: v = rstd_r*acc - (mu_r*rstd_r)*u[col] + w[col]; else v = acc + w[col]
// EPI: 0 store, 1 accumulate into C, 2 gelu
template<int EPI, int LNE>
__global__ __launch_bounds__(256) void gemm_m(
        const bf16* __restrict__ A, const bf16* __restrict__ Bt,
        const float* __restrict__ wv_, const float* __restrict__ uv_,
        const float* __restrict__ mu, const float* __restrict__ rstd,
        bf16* __restrict__ C, int M, int N, int K, int Kpad) {
    __shared__ __align__(16) short As[128 * 40];
    __shared__ __align__(16) short Bs[128 * 40];
    int bm = blockIdx.x * 128, bn = blockIdx.y * 128;
    int t = threadIdx.x, l = t & 63, w = t >> 6;
    int wr = (w >> 1) * 64, wc = (w & 1) * 64;
    int lr = l & 15, lk = (l >> 4) * 8;
    f4v acc[4][4];
    #pragma unroll
    for (int i = 0; i < 4; ++i)
        #pragma unroll
        for (int j = 0; j < 4; ++j) acc[i][j] = (f4v){0.f, 0.f, 0.f, 0.f};

    const short* Ash = (const short*)A;
    const short* Bsh = (const short*)Bt;
    for (int k0 = 0; k0 < Kpad; k0 += 32) {
        __syncthreads();
        #pragma unroll
        for (int i2 = 0; i2 < 2; ++i2) {
            int c = t * 2 + i2;
            int row = c >> 2, ko = (c & 3) * 8;
            *(s8v*)&As[row * 40 + ko] = *(const s8v*)(Ash + (size_t)(bm + row) * K + k0 + ko);
            *(s8v*)&Bs[row * 40 + ko] = *(const s8v*)(Bsh + (size_t)(bn + row) * Kpad + k0 + ko);
        }
        __syncthreads();
        s8v a[4], b[4];
        #pragma unroll
        for (int fi = 0; fi < 4; ++fi)
            a[fi] = *(const s8v*)&As[(wr + fi * 16 + lr) * 40 + lk];
        #pragma unroll
        for (int fj = 0; fj < 4; ++fj)
            b[fj] = *(const s8v*)&Bs[(wc + fj * 16 + lr) * 40 + lk];
        #pragma unroll
        for (int fi = 0; fi < 4; ++fi)
            #pragma unroll
            for (int fj = 0; fj < 4; ++fj)
                acc[fi][fj] = __builtin_amdgcn_mfma_f32_16x16x32_bf16(
                        a[fi], b[fj], acc[fi][fj], 0, 0, 0);
    }
    int r0 = (l >> 4) * 4;
    #pragma unroll
    for (int fi = 0; fi < 4; ++fi) {
        int rowb = bm + wr + fi * 16 + r0;
        float sr[4] = {1.f, 1.f, 1.f, 1.f}, tr[4] = {0.f, 0.f, 0.f, 0.f};
        if (LNE) {
            #pragma unroll
            for (int r = 0; r < 4; ++r) {
                sr[r] = rstd[rowb + r];
                tr[r] = mu[rowb + r] * sr[r];
            }
        }
        #pragma unroll
        for (int fj = 0; fj < 4; ++fj) {
            int col = bn + wc + fj * 16 + lr;
            if (col < N) {
                float ww = wv_[col];
                float uu = LNE ? uv_[col] : 0.f;
                #pragma unroll
                for (int r = 0; r < 4; ++r) {
                    size_t idx = (size_t)(rowb + r) * N + col;
                    float v = LNE ? (sr[r] * acc[fi][fj][r] - tr[r] * uu + ww)
                                  : (acc[fi][fj][r] + ww);
                    if (EPI == 1) v += b2f(C[idx]);
                    if (EPI == 2) v = gelu_f(v);
                    C[idx] = f2b(v);
                }
            }
        }
    }
}

// ---------------- FAVOR+ stages ----------------
__global__ void initkmax_kernel(unsigned* kmax_u) {
    if (threadIdx.x == 0) *kmax_u = 0x00800000u;   // enc(-FLT_MAX)
}

__global__ __launch_bounds__(256) void kmax_kernel(const bf16* __restrict__ k,
        const float* __restrict__ proj, unsigned* __restrict__ kmax_u) {
    __shared__ float4 pj4[NBF * 5];
    __shared__ float wmax[4];
    for (int i = threadIdx.x; i < NBF * 5; i += 256) pj4[i] = ((const float4*)proj)[i];
    __syncthreads();
    float mx = -3.4e38f;
    int total = NTOK * HEADS;
    for (int u = blockIdx.x * 256 + threadIdx.x; u < total; u += gridDim.x * 256) {
        int t = u / HEADS, h = u % HEADS;
        const ushort* kr = (const ushort*)k + (size_t)t * DIM + h * DH;
        float4 kn[5];
        #pragma unroll
        for (int q = 0; q < 5; ++q) {
            ushort4 u4 = ((const ushort4*)kr)[q];
            kn[q].x = bfu(u4.x) * SCALE; kn[q].y = bfu(u4.y) * SCALE;
            kn[q].z = bfu(u4.z) * SCALE; kn[q].w = bfu(u4.w) * SCALE;
        }
        for (int m = 0; m < NBF; ++m) {
            float dot = 0.f;
            #pragma unroll
            for (int q = 0; q < 5; ++q) {
                float4 p = pj4[m * 5 + q];
                dot += p.x * kn[q].x + p.y * kn[q].y + p.z * kn[q].z + p.w * kn[q].w;
            }
            mx = fmaxf(mx, dot);
        }
    }
    #pragma unroll
    for (int o = 32; o > 0; o >>= 1) mx = fmaxf(mx, __shfl_xor(mx, o));
    if ((threadIdx.x & 63) == 0) wmax[threadIdx.x >> 6] = mx;
    __syncthreads();
    if (threadIdx.x == 0) {
        float m2 = fmaxf(fmaxf(wmax[0], wmax[1]), fmaxf(wmax[2], wmax[3]));
        unsigned u = __float_as_uint(m2);
        u = (u & 0x80000000u) ? ~u : (u | 0x80000000u);
        atomicMax(kmax_u, u);
    }
}

// split-parallel kvctx: partial ctx/ksum per (n,h,split-slice)
__global__ __launch_bounds__(256) void kvctx_kernel(const bf16* __restrict__ k,
        const bf16* __restrict__ v, const float* __restrict__ proj,
        const unsigned* __restrict__ kmax_u,
        float* __restrict__ ctx_part, float* __restrict__ ksum_part) {
    __shared__ float projs[NBF * DH];
    __shared__ float ks[64][DH];
    __shared__ float vs[64][DH];
    __shared__ float kps[64][NBF + 1];
    __shared__ float diag[64];
    int b = blockIdx.x;
    int sp = b % SPLIT, nh = b / SPLIT;
    int n = nh / HEADS, h = nh % HEADS;
    for (int i = threadIdx.x; i < NBF * DH; i += 256) projs[i] = proj[i];
    unsigned su = *kmax_u;
    float kmax = (su & 0x80000000u) ? __uint_as_float(su & 0x7FFFFFFFu)
                                    : __uint_as_float(~su);
    float acc[5] = {0.f, 0.f, 0.f, 0.f, 0.f};
    float ksr = 0.f;
    const int cpb = 32 / SPLIT;
    for (int c = sp * cpb; c < (sp + 1) * cpb; ++c) {
        int s0 = c * 64;
        __syncthreads();
        for (int i = threadIdx.x; i < 64 * DH; i += 256) {
            int s = i / DH, d = i % DH;
            size_t base = ((size_t)(n * SEQ + s0 + s)) * DIM + h * DH + d;
            ks[s][d] = b2f(k[base]) * SCALE;
            vs[s][d] = b2f(v[base]);
        }
        __syncthreads();
        if (threadIdx.x < 64) {
            float dg = 0.f;
            #pragma unroll
            for (int d = 0; d < DH; ++d) { float tt = ks[threadIdx.x][d]; dg += tt * tt; }
            diag[threadIdx.x] = 0.5f * dg;
        }
        __syncthreads();
        for (int e = threadIdx.x; e < 64 * NBF; e += 256) {
            int s = e / NBF, m = e % NBF;
            float dot = 0.f;
            #pragma unroll
            for (int d = 0; d < DH; ++d) dot += ks[s][d] * projs[m * DH + d];
            kps[s][m] = RATIO * (__expf(dot - diag[s] - kmax) + KEPS);
        }
        __syncthreads();
        if (threadIdx.x < NBF) {
            float ss = 0.f;
            for (int s = 0; s < 64; ++s) ss += kps[s][threadIdx.x];
            ksr += ss;
        }
        #pragma unroll
        for (int r = 0; r < 5; ++r) {
            int p = threadIdx.x + r * 256;
            if (p < DH * NBF) {
                int d = p / NBF, m = p % NBF;
                float a = acc[r];
                for (int s = 0; s < 64; ++s) a += kps[s][m] * vs[s][d];
                acc[r] = a;
            }
        }
    }
    size_t ob = (size_t)(nh * SPLIT + sp);
    #pragma unroll
    for (int r = 0; r < 5; ++r) {
        int p = threadIdx.x + r * 256;
        if (p < DH * NBF) ctx_part[ob * (DH * NBF) + p] = acc[r];
    }
    if (threadIdx.x < NBF) ksum_part[ob * NBF + threadIdx.x] = ksr;
}

// in-place reduce: slice 0 of each (n,h) group accumulates slices 0..SPLIT-1
__global__ __launch_bounds__(256) void reduce_kernel(float* __restrict__ ctx_part,
        float* __restrict__ ksum_part) {
    int i = blockIdx.x * 256 + threadIdx.x;
    if (i < NSEQ * HEADS * DH * NBF) {
        int nh = i / (DH * NBF), p = i % (DH * NBF);
        float s = 0.f;
        for (int sp = 0; sp < SPLIT; ++sp)
            s += ctx_part[(size_t)(nh * SPLIT + sp) * (DH * NBF) + p];
        ctx_part[(size_t)(nh * SPLIT) * (DH * NBF) + p] = s;
    }
    if (i < NSEQ * HEADS * NBF) {
        int nh = i / NBF, m = i % NBF;
        float s = 0.f;
        for (int sp = 0; sp < SPLIT; ++sp)
            s += ksum_part[(size_t)(nh * SPLIT + sp) * NBF + m];
        ksum_part[(size_t)(nh * SPLIT) * NBF + m] = s;
    }
}

// per-(n,h,s): qp row, d_inv, output = qp@ctx * d_inv
__global__ __launch_bounds__(256) void qattn_kernel(const bf16* __restrict__ q,
        const float* __restrict__ proj, const float* __restrict__ ctx,
        const float* __restrict__ ksum, bf16* __restrict__ ao) {
    __shared__ float4 pj4[NBF * 5];
    __shared__ float4 cx4[NBF * 5];   // transposed [m][20]
    __shared__ float ksums[NBF];
    int b = blockIdx.x;
    int n = b / (HEADS * 8);
    int h = (b / 8) % HEADS;
    int sc = b % 8;
    int nh = n * HEADS + h;
    const float* cbase = ctx + (size_t)nh * SPLIT * (DH * NBF);
    for (int i = threadIdx.x; i < NBF * DH; i += 256) {
        int m = i / DH, d = i % DH;
        ((float*)cx4)[m * DH + d] = cbase[d * NBF + m];
        ((float*)pj4)[i] = proj[i];
    }
    if (threadIdx.x < NBF)
        ksums[threadIdx.x] = ksum[(size_t)nh * SPLIT * NBF + threadIdx.x];
    __syncthreads();
    int s = sc * 256 + threadIdx.x;
    size_t tok = (size_t)n * SEQ + s;
    const ushort* qr = (const ushort*)q + tok * DIM + h * DH;
    float4 qn[5];
    float dg = 0.f;
    #pragma unroll
    for (int q5 = 0; q5 < 5; ++q5) {
        ushort4 u4 = ((const ushort4*)qr)[q5];
        qn[q5].x = bfu(u4.x) * SCALE; qn[q5].y = bfu(u4.y) * SCALE;
        qn[q5].z = bfu(u4.z) * SCALE; qn[q5].w = bfu(u4.w) * SCALE;
        dg += qn[q5].x*qn[q5].x + qn[q5].y*qn[q5].y + qn[q5].z*qn[q5].z + qn[q5].w*qn[q5].w;
    }
    dg *= 0.5f;
    float mx = -3.4e38f;
    for (int m = 0; m < NBF; ++m) {
        float dot = 0.f;
        #pragma unroll
        for (int q5 = 0; q5 < 5; ++q5) {
            float4 p = pj4[m * 5 + q5];
            dot += p.x*qn[q5].x + p.y*qn[q5].y + p.z*qn[q5].z + p.w*qn[q5].w;
        }
        mx = fmaxf(mx, dot);
    }
    float den = 0.f;
    float4 o[5];
    #pragma unroll
    for (int q5 = 0; q5 < 5; ++q5) o[q5] = (float4){0.f, 0.f, 0.f, 0.f};
    for (int m = 0; m < NBF; ++m) {
        float dot = 0.f;
        #pragma unroll
        for (int q5 = 0; q5 < 5; ++q5) {
            float4 p = pj4[m * 5 + q5];
            dot += p.x*qn[q5].x + p.y*qn[q5].y + p.z*qn[q5].z + p.w*qn[q5].w;
        }
        float qp = RATIO * (__expf(dot - dg - mx) + KEPS);
        den += qp * ksums[m];
        #pragma unroll
        for (int q5 = 0; q5 < 5; ++q5) {
            float4 cv = cx4[m * 5 + q5];
            o[q5].x += qp * cv.x; o[q5].y += qp * cv.y;
            o[q5].z += qp * cv.z; o[q5].w += qp * cv.w;
        }
    }
    float dinv = 1.f / den;
    ushort* orow = (ushort*)ao + tok * DIM + h * DH;
    #pragma unroll
    for (int q5 = 0; q5 < 5; ++q5) {
        ushort4 o4;
        o4.x = f2u(o[q5].x * dinv); o4.y = f2u(o[q5].y * dinv);
        o4.z = f2u(o[q5].z * dinv); o4.w = f2u(o[q5].w * dinv);
        ((ushort4*)orow)[q5] = o4;
    }
}

// ---------------- pooling ----------------
__global__ __launch_bounds__(256) void pool1_kernel(const bf16* __restrict__ hn,
        float* __restrict__ partial) {
    int n = blockIdx.x / 16, c = blockIdx.x % 16;
    int d = threadIdx.x;
    if (d >= DIM) return;
    float acc = 0.f;
    const bf16* base = hn + ((size_t)n * SEQ + c * 128) * DIM + d;
    for (int s = 0; s < 128; ++s) acc += b2f(base[(size_t)s * DIM]);
    partial[(size_t)blockIdx.x * DIM + d] = acc;
}

__global__ __launch_bounds__(256) void pool2_kernel(const float* __restrict__ partial,
        float* __restrict__ pooled) {
    int n = blockIdx.x, d = threadIdx.x;
    if (d >= DIM) return;
    float acc = 0.f;
    for (int c = 0; c < 16; ++c) acc += partial[(size_t)(n * 16 + c) * DIM + d];
    pooled[n * DIM + d] = acc * (1.f / SEQ);
}

__global__ __launch_bounds__(512) void finalproj_kernel(const float* __restrict__ pooled,
        const float* __restrict__ pw, const float* __restrict__ pb,
        float* __restrict__ out) {
    __shared__ float ps[DIM];
    int n = blockIdx.x;
    for (int i = threadIdx.x; i < DIM; i += 512) ps[i] = pooled[n * DIM + i];
    __syncthreads();
    int j = threadIdx.x;
    float acc = pb[j];
    for (int d = 0; d < DIM; ++d) acc += ps[d] * pw[d * DMODEL + j];
    out[n * DMODEL + j] = acc;
}

// ---------------- host launch ----------------
extern "C" void kernel_launch(void* const* d_in, const int* in_sizes, int n_in,
                              void* d_out, int out_size, void* d_ws, size_t ws_size,
                              hipStream_t stream) {
    (void)in_sizes; (void)n_in; (void)out_size;
    const float* x    = (const float*)d_in[0];
    const float* emb  = (const float*)d_in[1];
    const float* ln1g = (const float*)d_in[2];
    const float* ln1b = (const float*)d_in[3];
    const float* wq   = (const float*)d_in[4];
    const float* bq   = (const float*)d_in[5];
    const float* wk   = (const float*)d_in[6];
    const float* bk   = (const float*)d_in[7];
    const float* wv   = (const float*)d_in[8];
    const float* bv   = (const float*)d_in[9];
    const float* proj = (const float*)d_in[10];
    const float* wo   = (const float*)d_in[11];
    const float* bo   = (const float*)d_in[12];
    const float* ln2g = (const float*)d_in[13];
    const float* ln2b = (const float*)d_in[14];
    const float* ffw1 = (const float*)d_in[15];
    const float* ffb1 = (const float*)d_in[16];
    const float* ffw2 = (const float*)d_in[17];
    const float* ffb2 = (const float*)d_in[18];
    const float* lnfg = (const float*)d_in[19];
    const float* lnfb = (const float*)d_in[20];
    const float* pw   = (const float*)d_in[21];
    const float* pb   = (const float*)d_in[22];
    float* out = (float*)d_out;

    const size_t A_ = (size_t)NTOK * DIM;
    bf16* x1 = (bf16*)d_ws;
    bf16* x2 = x1 + A_ + BUFPAD;
    bf16* b3 = x2 + A_ + BUFPAD;     // k -> q ; FF hidden spans b3..b4
    bf16* b4 = b3 + A_ + BUFPAD;     // v -> attn out
    bf16* panel1 = b4 + A_ + BUFPAD;           // [896*224] max
    bf16* panel2 = panel1 + P1ELEM;            // [256*800]
    float* muB   = (float*)(panel2 + P2ELEM);
    float* rstdB = muB + NTOK;
    float* uw    = rstdB + NTOK;               // 3328 floats
    float* ctx_part  = uw + 3328;                            // 640*SPLIT*1180
    float* ksum_part = ctx_part + (size_t)NSEQ*HEADS*SPLIT*DH*NBF;  // 640*SPLIT*59
    unsigned* kmaxu  = (unsigned*)(ksum_part + (size_t)NSEQ*HEADS*SPLIT*NBF);

    float* uq = uw,        *uk = uw + 256,  *uv = uw + 512;
    float* wqf = uw + 768, *wkf = uw + 1024, *wvf = uw + 1280;
    float* u1 = uw + 1536, *w1f = uw + 2432;

    size_t need = (char*)(kmaxu + 16) - (char*)d_ws;
    if (ws_size < need) {
        sentinel_kernel<<<1, 64, 0, stream>>>(out, (float)(ws_size >> 20));
        return;
    }

    zeropad_kernel<<<1, 64, 0, stream>>>(x1 + A_, x2 + A_, b3 + A_, b4 + A_);
    embed_kernel<<<(NTOK * 25 + 255) / 256, 256, 0, stream>>>(x, emb, x1, x2);

    dim3 gqkv(NTOK / 128, 2);
    dim3 gff1(CHROWS / 128, 7);
    dim3 gff2(CHROWS / 128, 2);
    const int PB = 256;   // prep_panel block
    for (int l = 0; l < DEPTH; ++l) {
        const float* wq_l = wq + (size_t)l * DIM * DIM;
        const float* wk_l = wk + (size_t)l * DIM * DIM;
        const float* wv_l = wv + (size_t)l * DIM * DIM;
        const float* wo_l = wo + (size_t)l * DIM * DIM;
        const float* f1_l = ffw1 + (size_t)l * DIM * FFD;
        const float* f2_l = ffw2 + (size_t)l * FFD * DIM;
        const float* pj_l = proj + (size_t)l * NBF * DH;
        const float* g1 = ln1g + l * DIM, *b1 = ln1b + l * DIM;
        const float* g2 = ln2g + l * DIM, *b2 = ln2b + l * DIM;

        lnstats_kernel<<<NTOK / 4, 256, 0, stream>>>(x2, muB, rstdB);
        prep_uw<<<1, PB, 0, stream>>>(wk_l, g1, b1, bk + l * DIM, uk, wkf, DIM, DIM);
        prep_uw<<<1, PB, 0, stream>>>(wv_l, g1, b1, bv + l * DIM, uv, wvf, DIM, DIM);
        prep_uw<<<1, PB, 0, stream>>>(wq_l, g1, b1, bq + l * DIM, uq, wqf, DIM, DIM);

        // k -> b3
        prep_panel<<<(256 * KPAD + PB - 1) / PB, PB, 0, stream>>>(wk_l, g1, panel1, DIM, DIM, 256, KPAD);
        gemm_m<0, 1><<<gqkv, 256, 0, stream>>>(x2, panel1, wkf, uk, muB, rstdB,
                b3, NTOK, DIM, DIM, KPAD);
        initkmax_kernel<<<1, 64, 0, stream>>>(kmaxu);
        kmax_kernel<<<2048, 256, 0, stream>>>(b3, pj_l, kmaxu);
        // v -> b4
        prep_panel<<<(256 * KPAD + PB - 1) / PB, PB, 0, stream>>>(wv_l, g1, panel1, DIM, DIM, 256, KPAD);
        gemm_m<0, 1><<<gqkv, 256, 0, stream>>>(x2, panel1, wvf, uv, muB, rstdB,
                b4, NTOK, DIM, DIM, KPAD);
        kvctx_kernel<<<NSEQ * HEADS * SPLIT, 256, 0, stream>>>(b3, b4, pj_l, kmaxu,
                ctx_part, ksum_part);
        reduce_kernel<<<(NSEQ * HEADS * DH * NBF + 255) / 256, 256, 0, stream>>>(
                ctx_part, ksum_part);
        // q -> b3 (k dead)
        prep_panel<<<(256 * KPAD + PB - 1) / PB, PB, 0, stream>>>(wq_l, g1, panel1, DIM, DIM, 256, KPAD);
        gemm_m<0, 1><<<gqkv, 256, 0, stream>>>(x2, panel1, wqf, uq, muB, rstdB,
                b3, NTOK, DIM, DIM, KPAD);
        // attn out -> b4 (v dead)
        qattn_kernel<<<NSEQ * HEADS * 8, 256, 0, stream>>>(b3, pj_l, ctx_part, ksum_part, b4);
        // x1 += b4 @ wo + bo
        prep_panel<<<(256 * KPAD + PB - 1) / PB, PB, 0, stream>>>(wo_l, nullptr, panel1, DIM, DIM, 256, KPAD);
        gemm_m<1, 0><<<gqkv, 256, 0, stream>>>(b4, panel1, bo + l * DIM, nullptr,
                nullptr, nullptr, x1, NTOK, DIM, DIM, KPAD);

        // FF
        lnstats_kernel<<<NTOK / 4, 256, 0, stream>>>(x1, muB, rstdB);
        prep_uw<<<(FFD + PB - 1) / PB, PB, 0, stream>>>(f1_l, g2, b2, ffb1 + l * FFD, u1, w1f, FFD, DIM);
        prep_panel<<<(896 * KPAD + PB - 1) / PB, PB, 0, stream>>>(f1_l, g2, panel1, FFD, DIM, 896, KPAD);
        prep_panel<<<(256 * 800 + PB - 1) / PB, PB, 0, stream>>>(f2_l, nullptr, panel2, DIM, FFD, 256, 800);
        for (int c = 0; c < NCHUNK; ++c) {
            size_t roff = (size_t)c * CHROWS;
            bf16* hid = b3;   // spans b3..b4 (2A elems)
            gemm_m<2, 1><<<gff1, 256, 0, stream>>>(x1 + roff * DIM, panel1, w1f, u1,
                    muB + roff, rstdB + roff, hid, CHROWS, FFD, DIM, KPAD);
            gemm_m<1, 0><<<gff2, 256, 0, stream>>>(hid, panel2, ffb2 + l * DIM, nullptr,
                    nullptr, nullptr, x2 + roff * DIM, CHROWS, DIM, FFD, FFD);
        }
    }

    // h = LN_f(0.5*(x1+x2)) -> b3 ; pooled ; out = pooled@pw + pb
    finalln_kernel<<<NTOK / 4, 256, 0, stream>>>(x1, x2, lnfg, lnfb, b3);
    float* partial = muB;                       // overlay, dead now
    float* pooled  = muB + (size_t)NSEQ * 16 * DIM;
    pool1_kernel<<<NSEQ * 16, 256, 0, stream>>>(b3, partial);
    pool2_kernel<<<NSEQ, 256, 0, stream>>>(partial, pooled);
    finalproj_kernel<<<NSEQ, 512, 0, stream>>>(pooled, pw, pb, out);
}

// Round 5
// 5933.862 us; speedup vs baseline: 4.3845x; 1.5357x over previous
//
#include <hip/hip_runtime.h>
#include <hip/hip_bf16.h>
#include <math.h>

#define DEPTH   6
#define DIM     200
#define HEADS   10
#define DH      20
#define NBF     59
#define FFD     800
#define DMODEL  512
#define NSEQ    64
#define SEQ     2048
#define NTOK    (NSEQ*SEQ)   // 131072
#define NCHUNK  2
#define CHROWS  (NTOK/NCHUNK)
#define KPAD    224          // ceil(200/32)*32
#define BUFPAD  64
#define P1ELEM  (896*KPAD)   // panel1 max: ffw1 [896][224]
#define P2ELEM  (256*800)    // panel2: ffw2 [256][800]
#define KNROW   40           // staged row stride (shorts) for kn/qn/proj
#define VROW    136          // vT row stride
#define KPROW   136          // kp row stride
#define QPROW   72           // qp / ctxT row stride
#define CTXR    21           // ctx rows stored (d=0..19 + ksum row 20)

typedef __hip_bfloat16 bf16;
typedef unsigned short u16;
typedef short s8v __attribute__((ext_vector_type(8)));
typedef short s4v __attribute__((ext_vector_type(4)));
typedef float f4v __attribute__((ext_vector_type(4)));

constexpr float SCALE = 0.4728708045015879f;   // 20^-0.25
constexpr float RATIO = 0.1301889109808239f;   // 59^-0.5
constexpr float KEPS  = 1e-4f;

__device__ __forceinline__ float b2f(bf16 v) { return __bfloat162float(v); }
__device__ __forceinline__ bf16 f2b(float v) { return __float2bfloat16(v); }
__device__ __forceinline__ float bfu(u16 u) {
    return __uint_as_float(((unsigned)u) << 16);
}
__device__ __forceinline__ u16 f2u(float v) {
    bf16 hb = __float2bfloat16(v);
    return *(u16*)&hb;
}
__device__ __forceinline__ float gelu_f(float x) {
    return 0.5f * x * (1.f + erff(x * 0.70710678118654752f));
}
#define MFMA16(a, b, c) __builtin_amdgcn_mfma_f32_16x16x32_bf16(a, b, c, 0, 0, 0)

// ---------------- sentinel: encodes ws_size(MB) into out[0] ----------------
__global__ void sentinel_kernel(float* out, float wsmb) {
    if (threadIdx.x == 0) out[0] = wsmb;
}

__global__ void zeropad_kernel(bf16* p1, bf16* p2, bf16* p3, bf16* p4) {
    int i = threadIdx.x;
    if (i < BUFPAD) {
        bf16 z = f2b(0.f);
        p1[i] = z; p2[i] = z; p3[i] = z; p4[i] = z;
    }
}

// ------- panel prep: bf16, transposed [Npad][Kpad], zero-pad, opt g-fold ----
__global__ __launch_bounds__(256) void prep_panel(const float* __restrict__ W,
        const float* __restrict__ g, bf16* __restrict__ panel,
        int N, int K, int Npad, int Kpad) {
    int idx = blockIdx.x * 256 + threadIdx.x;
    if (idx >= Npad * Kpad) return;
    int n = idx / Kpad, k = idx % Kpad;
    float v = 0.f;
    if (n < N && k < K) {
        v = W[(size_t)k * N + n];
        if (g) v *= g[k];
    }
    panel[idx] = f2b(v);
}

// u[n] = sum_k g[k]W[k,n]; w[n] = sum_k b[k]W[k,n] + bias[n]
__global__ __launch_bounds__(256) void prep_uw(const float* __restrict__ W,
        const float* __restrict__ g, const float* __restrict__ bln,
        const float* __restrict__ bias, float* __restrict__ u,
        float* __restrict__ w, int N, int K) {
    int n = blockIdx.x * 256 + threadIdx.x;
    if (n >= N) return;
    float su = 0.f, sw = 0.f;
    for (int k = 0; k < K; ++k) {
        float wv = W[(size_t)k * N + n];
        su += g[k] * wv;
        sw += bln[k] * wv;
    }
    u[n] = su;
    w[n] = sw + bias[n];
}

// fused q/k/v variant: one launch, 3 blocks
__global__ __launch_bounds__(256) void prep_uw_qkv(
        const float* __restrict__ wq, const float* __restrict__ wk,
        const float* __restrict__ wv, const float* __restrict__ g,
        const float* __restrict__ bln, const float* __restrict__ bq,
        const float* __restrict__ bk, const float* __restrict__ bv,
        float* __restrict__ uw) {
    int which = blockIdx.x;
    const float* W    = which == 0 ? wq : (which == 1 ? wk : wv);
    const float* bias = which == 0 ? bq : (which == 1 ? bk : bv);
    float* u  = uw + which * 256;
    float* wf = uw + 768 + which * 256;
    int n = threadIdx.x;
    if (n >= DIM) return;
    float su = 0.f, sw = 0.f;
    for (int k = 0; k < DIM; ++k) {
        float t = W[(size_t)k * DIM + n];
        su += g[k] * t;
        sw += bln[k] * t;
    }
    u[n] = su;
    wf[n] = sw + bias[n];
}

// ---------------- embedding: tokens are 1 (x<=0) or 5 (x>0) ----------------
__global__ __launch_bounds__(256) void embed_kernel(const float* __restrict__ x,
        const float* __restrict__ emb, bf16* __restrict__ x1, bf16* __restrict__ x2) {
    int idx = blockIdx.x * 256 + threadIdx.x;      // NTOK*25
    if (idx >= NTOK * 25) return;
    int t = idx / 25, c = idx % 25;
    int row = (x[t] > 0.f) ? 5 : 1;
    const float4* e4 = (const float4*)(emb + row * DIM + c * 8);
    float4 e0 = e4[0], e1 = e4[1];
    s8v o;
    o[0] = (short)f2u(e0.x); o[1] = (short)f2u(e0.y);
    o[2] = (short)f2u(e0.z); o[3] = (short)f2u(e0.w);
    o[4] = (short)f2u(e1.x); o[5] = (short)f2u(e1.y);
    o[6] = (short)f2u(e1.z); o[7] = (short)f2u(e1.w);
    size_t off = (size_t)t * DIM + c * 8;
    *(s8v*)((short*)x1 + off) = o;
    *(s8v*)((short*)x2 + off) = o;
}

// ---------------- LN stats (one wave per token row of 200) ----------------
__global__ __launch_bounds__(256) void lnstats_kernel(const bf16* __restrict__ in,
        float* __restrict__ mu_o, float* __restrict__ rstd_o) {
    int lane = threadIdx.x & 63;
    size_t t = (size_t)blockIdx.x * 4 + (threadIdx.x >> 6);
    const u16* row = (const u16*)in + t * DIM;
    float v0 = 0.f, v1 = 0.f, v2 = 0.f, v3 = 0.f;
    if (lane < 50) {
        ushort4 u4 = ((const ushort4*)row)[lane];
        v0 = bfu(u4.x); v1 = bfu(u4.y); v2 = bfu(u4.z); v3 = bfu(u4.w);
    }
    float s = v0 + v1 + v2 + v3, qq = v0*v0 + v1*v1 + v2*v2 + v3*v3;
    #pragma unroll
    for (int o = 32; o > 0; o >>= 1) { s += __shfl_xor(s, o); qq += __shfl_xor(qq, o); }
    if (lane == 0) {
        float mu = s * (1.f / DIM);
        mu_o[t] = mu;
        rstd_o[t] = rsqrtf(qq * (1.f / DIM) - mu * mu + 1e-5f);
    }
}

__global__ __launch_bounds__(256) void finalln_kernel(const bf16* __restrict__ in1,
        const bf16* __restrict__ in2, const float* __restrict__ g,
        const float* __restrict__ b, bf16* __restrict__ out) {
    int lane = threadIdx.x & 63;
    size_t t = (size_t)blockIdx.x * 4 + (threadIdx.x >> 6);
    const u16* r1 = (const u16*)in1 + t * DIM;
    const u16* r2 = (const u16*)in2 + t * DIM;
    float v0 = 0.f, v1 = 0.f, v2 = 0.f, v3 = 0.f;
    if (lane < 50) {
        ushort4 a4 = ((const ushort4*)r1)[lane];
        ushort4 b4 = ((const ushort4*)r2)[lane];
        v0 = 0.5f * (bfu(a4.x) + bfu(b4.x));
        v1 = 0.5f * (bfu(a4.y) + bfu(b4.y));
        v2 = 0.5f * (bfu(a4.z) + bfu(b4.z));
        v3 = 0.5f * (bfu(a4.w) + bfu(b4.w));
    }
    float s = v0 + v1 + v2 + v3, qq = v0*v0 + v1*v1 + v2*v2 + v3*v3;
    #pragma unroll
    for (int o = 32; o > 0; o >>= 1) { s += __shfl_xor(s, o); qq += __shfl_xor(qq, o); }
    float mu = s * (1.f / DIM);
    float rstd = rsqrtf(qq * (1.f / DIM) - mu * mu + 1e-5f);
    if (lane < 50) {
        float4 g4 = ((const float4*)g)[lane];
        float4 b4f = ((const float4*)b)[lane];
        ushort4 o4;
        o4.x = f2u((v0 - mu) * rstd * g4.x + b4f.x);
        o4.y = f2u((v1 - mu) * rstd * g4.y + b4f.y);
        o4.z = f2u((v2 - mu) * rstd * g4.z + b4f.z);
        o4.w = f2u((v3 - mu) * rstd * g4.w + b4f.w);
        ((ushort4*)((u16*)out + t * DIM))[lane] = o4;
    }
}

// ---------------- MFMA GEMM: C = epi(A @ Bt^T) + LN-epilogue ----------------
template<int EPI, int LNE>
__global__ __launch_bounds__(256) void gemm_m(
        const bf16* __restrict__ A, const bf16* __restrict__ Bt,
        const float* __restrict__ wv_, const float* __restrict__ uv_,
        const float* __restrict__ mu, const float* __restrict__ rstd,
        bf16* __restrict__ C, int M, int N, int K, int Kpad) {
    __shared__ __align__(16) short As[128 * 40];
    __shared__ __align__(16) short Bs[128 * 40];
    int bm = blockIdx.x * 128, bn = blockIdx.y * 128;
    int t = threadIdx.x, l = t & 63, w = t >> 6;
    int wr = (w >> 1) * 64, wc = (w & 1) * 64;
    int lr = l & 15, lk = (l >> 4) * 8;
    f4v acc[4][4];
    #pragma unroll
    for (int i = 0; i < 4; ++i)
        #pragma unroll
        for (int j = 0; j < 4; ++j) acc[i][j] = (f4v){0.f, 0.f, 0.f, 0.f};

    const short* Ash = (const short*)A;
    const short* Bsh = (const short*)Bt;
    s8v pa[2], pb[2];
    #pragma unroll
    for (int i2 = 0; i2 < 2; ++i2) {
        int c = t * 2 + i2;
        int row = c >> 2, ko = (c & 3) * 8;
        pa[i2] = *(const s8v*)(Ash + (size_t)(bm + row) * K + ko);
        pb[i2] = *(const s8v*)(Bsh + (size_t)(bn + row) * Kpad + ko);
    }
    for (int k0 = 0; k0 < Kpad; k0 += 32) {
        __syncthreads();
        #pragma unroll
        for (int i2 = 0; i2 < 2; ++i2) {
            int c = t * 2 + i2;
            int row = c >> 2, ko = (c & 3) * 8;
            *(s8v*)&As[row * 40 + ko] = pa[i2];
            *(s8v*)&Bs[row * 40 + ko] = pb[i2];
        }
        __syncthreads();
        if (k0 + 32 < Kpad) {
            #pragma unroll
            for (int i2 = 0; i2 < 2; ++i2) {
                int c = t * 2 + i2;
                int row = c >> 2, ko = (c & 3) * 8;
                pa[i2] = *(const s8v*)(Ash + (size_t)(bm + row) * K + k0 + 32 + ko);
                pb[i2] = *(const s8v*)(Bsh + (size_t)(bn + row) * Kpad + k0 + 32 + ko);
            }
        }
        s8v a[4], b[4];
        #pragma unroll
        for (int fi = 0; fi < 4; ++fi)
            a[fi] = *(const s8v*)&As[(wr + fi * 16 + lr) * 40 + lk];
        #pragma unroll
        for (int fj = 0; fj < 4; ++fj)
            b[fj] = *(const s8v*)&Bs[(wc + fj * 16 + lr) * 40 + lk];
        #pragma unroll
        for (int fi = 0; fi < 4; ++fi)
            #pragma unroll
            for (int fj = 0; fj < 4; ++fj)
                acc[fi][fj] = MFMA16(a[fi], b[fj], acc[fi][fj]);
    }
    int r0 = (l >> 4) * 4;
    #pragma unroll
    for (int fi = 0; fi < 4; ++fi) {
        int rowb = bm + wr + fi * 16 + r0;
        float sr[4] = {1.f, 1.f, 1.f, 1.f}, tr[4] = {0.f, 0.f, 0.f, 0.f};
        if (LNE) {
            #pragma unroll
            for (int r = 0; r < 4; ++r) {
                sr[r] = rstd[rowb + r];
                tr[r] = mu[rowb + r] * sr[r];
            }
        }
        #pragma unroll
        for (int fj = 0; fj < 4; ++fj) {
            int col = bn + wc + fj * 16 + lr;
            if (col < N) {
                float ww = wv_[col];
                float uu = LNE ? uv_[col] : 0.f;
                #pragma unroll
                for (int r = 0; r < 4; ++r) {
                    size_t idx = (size_t)(rowb + r) * N + col;
                    float v = LNE ? (sr[r] * acc[fi][fj][r] - tr[r] * uu + ww)
                                  : (acc[fi][fj][r] + ww);
                    if (EPI == 1) v += b2f(C[idx]);
                    if (EPI == 2) v = gelu_f(v);
                    C[idx] = f2b(v);
                }
            }
        }
    }
}

// ---------------- FAVOR+ stages ----------------
__global__ void initkmax_kernel(unsigned* kmax_u) {
    if (threadIdx.x == 0) *kmax_u = 0x00800000u;   // enc(-FLT_MAX)
}

__global__ __launch_bounds__(256) void kmax_kernel(const bf16* __restrict__ k,
        const float* __restrict__ proj, unsigned* __restrict__ kmax_u) {
    __shared__ float4 pj4[NBF * 5];
    __shared__ float wmax[4];
    for (int i = threadIdx.x; i < NBF * 5; i += 256) pj4[i] = ((const float4*)proj)[i];
    __syncthreads();
    float mx = -3.4e38f;
    int total = NTOK * HEADS;
    for (int u = blockIdx.x * 256 + threadIdx.x; u < total; u += gridDim.x * 256) {
        int t = u / HEADS, h = u % HEADS;
        const u16* kr = (const u16*)k + (size_t)t * DIM + h * DH;
        float4 kn[5];
        #pragma unroll
        for (int q = 0; q < 5; ++q) {
            ushort4 u4 = ((const ushort4*)kr)[q];
            kn[q].x = bfu(u4.x) * SCALE; kn[q].y = bfu(u4.y) * SCALE;
            kn[q].z = bfu(u4.z) * SCALE; kn[q].w = bfu(u4.w) * SCALE;
        }
        for (int m = 0; m < NBF; ++m) {
            float dot = 0.f;
            #pragma unroll
            for (int q = 0; q < 5; ++q) {
                float4 p = pj4[m * 5 + q];
                dot += p.x * kn[q].x + p.y * kn[q].y + p.z * kn[q].z + p.w * kn[q].w;
            }
            mx = fmaxf(mx, dot);
        }
    }
    #pragma unroll
    for (int o = 32; o > 0; o >>= 1) mx = fmaxf(mx, __shfl_xor(mx, o));
    if ((threadIdx.x & 63) == 0) wmax[threadIdx.x >> 6] = mx;
    __syncthreads();
    if (threadIdx.x == 0) {
        float m2 = fmaxf(fmaxf(wmax[0], wmax[1]), fmaxf(wmax[2], wmax[3]));
        unsigned u = __float_as_uint(m2);
        u = (u & 0x80000000u) ? ~u : (u | 0x80000000u);
        atomicMax(kmax_u, u);
    }
}

// ---- MFMA kvctx: per (n,h): ctxg[nh][d][m] (d=0..19 ctx, d=20 ksum) --------
__global__ __launch_bounds__(256) void kvctx_mfma(const bf16* __restrict__ k,
        const bf16* __restrict__ v, const float* __restrict__ proj,
        const unsigned* __restrict__ kmax_u, float* __restrict__ ctxg) {
    __shared__ __align__(16) short ph[64 * KNROW];
    __shared__ __align__(16) short pl[64 * KNROW];
    __shared__ __align__(16) short knh[128 * KNROW];
    __shared__ __align__(16) short knl[128 * KNROW];
    __shared__ __align__(16) short vT[32 * VROW];
    __shared__ __align__(16) short kp[64 * KPROW];
    __shared__ __align__(16) float diag[128];
    int nh = blockIdx.x, n = nh / HEADS, h = nh % HEADS;
    int t = threadIdx.x, l = t & 63, w = t >> 6;
    int lr = l & 15, lk = (l >> 4) * 8, l4 = (l >> 4) * 4;
    // stage proj hi/lo
    for (int i = t; i < 64 * 32; i += 256) {
        int m = i >> 5, d = i & 31;
        float val = (m < NBF && d < DH) ? proj[m * DH + d] : 0.f;
        u16 hi = f2u(val);
        ph[m * KNROW + d] = (short)hi;
        pl[m * KNROW + d] = (short)f2u(val - bfu(hi));
    }
    // zero pads: kn cols 20..31; vT rows 20..31 (row 20 = ones for ksum trick)
    for (int i = t; i < 128 * 12; i += 256) {
        int s = i / 12, d = 20 + i % 12;
        knh[s * KNROW + d] = 0; knl[s * KNROW + d] = 0;
    }
    for (int i = t; i < 12 * 128; i += 256) {
        int d = 20 + (i >> 7), s = i & 127;
        vT[d * VROW + s] = (short)((d == 20) ? f2u(1.0f) : 0);
    }
    unsigned su = *kmax_u;
    float kmax = (su & 0x80000000u) ? __uint_as_float(su & 0x7FFFFFFFu)
                                    : __uint_as_float(~su);
    f4v cd0 = {0.f, 0.f, 0.f, 0.f}, cd1 = {0.f, 0.f, 0.f, 0.f};
    for (int c = 0; c < 16; ++c) {
        int s0 = c * 128;
        __syncthreads();
        if (t < 128) {          // waves 0,1: stage kn hi/lo + diag
            int s = t;
            const u16* kr = (const u16*)k + ((size_t)(n * SEQ + s0 + s)) * DIM + h * DH;
            float dg = 0.f;
            #pragma unroll
            for (int q5 = 0; q5 < 5; ++q5) {
                ushort4 u4 = ((const ushort4*)kr)[q5];
                float f0 = bfu(u4.x) * SCALE, f1 = bfu(u4.y) * SCALE;
                float f2_ = bfu(u4.z) * SCALE, f3 = bfu(u4.w) * SCALE;
                dg += f0*f0 + f1*f1 + f2_*f2_ + f3*f3;
                u16 h0 = f2u(f0), h1 = f2u(f1), h2 = f2u(f2_), h3 = f2u(f3);
                s4v hv = {(short)h0, (short)h1, (short)h2, (short)h3};
                *(s4v*)&knh[s * KNROW + q5 * 4] = hv;
                s4v lv = {(short)f2u(f0 - bfu(h0)), (short)f2u(f1 - bfu(h1)),
                          (short)f2u(f2_ - bfu(h2)), (short)f2u(f3 - bfu(h3))};
                *(s4v*)&knl[s * KNROW + q5 * 4] = lv;
            }
            diag[s] = 0.5f * dg;
        } else {                // waves 2,3: stage vT (scatter to [d][s])
            int s = t - 128;
            const u16* vr = (const u16*)v + ((size_t)(n * SEQ + s0 + s)) * DIM + h * DH;
            #pragma unroll
            for (int q5 = 0; q5 < 5; ++q5) {
                ushort4 u4 = ((const ushort4*)vr)[q5];
                vT[(q5 * 4 + 0) * VROW + s] = (short)u4.x;
                vT[(q5 * 4 + 1) * VROW + s] = (short)u4.y;
                vT[(q5 * 4 + 2) * VROW + s] = (short)u4.z;
                vT[(q5 * 4 + 3) * VROW + s] = (short)u4.w;
            }
        }
        __syncthreads();
        // dash MFMA: wave w owns s-tiles {2w, 2w+1}, all 4 m-tiles
        s8v ah0 = *(const s8v*)&knh[(32 * w + lr) * KNROW + lk];
        s8v al0 = *(const s8v*)&knl[(32 * w + lr) * KNROW + lk];
        s8v ah1 = *(const s8v*)&knh[(32 * w + 16 + lr) * KNROW + lk];
        s8v al1 = *(const s8v*)&knl[(32 * w + 16 + lr) * KNROW + lk];
        f4v dg0 = *(const f4v*)&diag[32 * w + l4];
        f4v dg1 = *(const f4v*)&diag[32 * w + 16 + l4];
        #pragma unroll
        for (int mt = 0; mt < 4; ++mt) {
            s8v bh = *(const s8v*)&ph[(mt * 16 + lr) * KNROW + lk];
            s8v bl = *(const s8v*)&pl[(mt * 16 + lr) * KNROW + lk];
            f4v d0 = {0.f, 0.f, 0.f, 0.f}, d1 = {0.f, 0.f, 0.f, 0.f};
            d0 = MFMA16(ah0, bh, d0); d0 = MFMA16(ah0, bl, d0); d0 = MFMA16(al0, bh, d0);
            d1 = MFMA16(ah1, bh, d1); d1 = MFMA16(ah1, bl, d1); d1 = MFMA16(al1, bh, d1);
            int m = mt * 16 + lr;
            bool valid = m < NBF;
            s4v o0, o1;
            #pragma unroll
            for (int r = 0; r < 4; ++r) {
                float kp0 = valid ? RATIO * (__expf(d0[r] - dg0[r] - kmax) + KEPS) : 0.f;
                float kp1 = valid ? RATIO * (__expf(d1[r] - dg1[r] - kmax) + KEPS) : 0.f;
                o0[r] = (short)f2u(kp0);
                o1[r] = (short)f2u(kp1);
            }
            *(s4v*)&kp[m * KPROW + 32 * w + l4] = o0;
            *(s4v*)&kp[m * KPROW + 32 * w + 16 + l4] = o1;
        }
        __syncthreads();
        // ctx MFMA: wave w owns m-tile w (rows 16w..16w+15), both d-tiles, K=128
        #pragma unroll
        for (int ks = 0; ks < 4; ++ks) {
            s8v a  = *(const s8v*)&kp[(16 * w + lr) * KPROW + ks * 32 + lk];
            s8v b0 = *(const s8v*)&vT[lr * VROW + ks * 32 + lk];
            s8v b1 = *(const s8v*)&vT[(16 + lr) * VROW + ks * 32 + lk];
            cd0 = MFMA16(a, b0, cd0);
            cd1 = MFMA16(a, b1, cd1);
        }
    }
    // write ctxg[nh][d][m]: cd tile D[i=m][j=d]: col=lr=d, row m=16w+l4+r
    float* cg = ctxg + (size_t)nh * CTXR * 64;
    int m0 = 16 * w + l4;
    *(f4v*)&cg[lr * 64 + m0] = cd0;
    if (lr < 5) *(f4v*)&cg[(16 + lr) * 64 + m0] = cd1;   // d=16..20 (20 = ksum)
}

// ---- MFMA qattn: out = (qp @ ctx) * dinv via ksum column -------------------
__global__ __launch_bounds__(256) void qattn_mfma(const bf16* __restrict__ q,
        const float* __restrict__ proj, const float* __restrict__ ctxg,
        bf16* __restrict__ ao) {
    __shared__ __align__(16) short ph[64 * KNROW];
    __shared__ __align__(16) short pl[64 * KNROW];
    __shared__ __align__(16) short qnh[128 * KNROW];
    __shared__ __align__(16) short qnl[128 * KNROW];
    __shared__ __align__(16) short qp[128 * QPROW];
    __shared__ __align__(16) short cT[32 * QPROW];
    __shared__ __align__(16) float dgs[128];
    int nh = blockIdx.x, n = nh / HEADS, h = nh % HEADS;
    int t = threadIdx.x, l = t & 63, w = t >> 6;
    int lr = l & 15, lk = (l >> 4) * 8, l4 = (l >> 4) * 4;
    for (int i = t; i < 64 * 32; i += 256) {
        int m = i >> 5, d = i & 31;
        float val = (m < NBF && d < DH) ? proj[m * DH + d] : 0.f;
        u16 hi = f2u(val);
        ph[m * KNROW + d] = (short)hi;
        pl[m * KNROW + d] = (short)f2u(val - bfu(hi));
    }
    for (int i = t; i < 128 * 12; i += 256) {
        int s = i / 12, d = 20 + i % 12;
        qnh[s * KNROW + d] = 0; qnl[s * KNROW + d] = 0;
    }
    for (int i = t; i < 32 * 64; i += 256) {
        int d = i >> 6, m = i & 63;
        float val = (d < CTXR) ? ctxg[(size_t)nh * CTXR * 64 + d * 64 + m] : 0.f;
        cT[d * QPROW + m] = (short)f2u(val);
    }
    for (int c = 0; c < 16; ++c) {
        int s0 = c * 128;
        __syncthreads();
        if (t < 128) {
            int s = t;
            const u16* qr = (const u16*)q + ((size_t)(n * SEQ + s0 + s)) * DIM + h * DH;
            float dg = 0.f;
            #pragma unroll
            for (int q5 = 0; q5 < 5; ++q5) {
                ushort4 u4 = ((const ushort4*)qr)[q5];
                float f0 = bfu(u4.x) * SCALE, f1 = bfu(u4.y) * SCALE;
                float f2_ = bfu(u4.z) * SCALE, f3 = bfu(u4.w) * SCALE;
                dg += f0*f0 + f1*f1 + f2_*f2_ + f3*f3;
                u16 h0 = f2u(f0), h1 = f2u(f1), h2 = f2u(f2_), h3 = f2u(f3);
                s4v hv = {(short)h0, (short)h1, (short)h2, (short)h3};
                *(s4v*)&qnh[s * KNROW + q5 * 4] = hv;
                s4v lv = {(short)f2u(f0 - bfu(h0)), (short)f2u(f1 - bfu(h1)),
                          (short)f2u(f2_ - bfu(h2)), (short)f2u(f3 - bfu(h3))};
                *(s4v*)&qnl[s * KNROW + q5 * 4] = lv;
            }
            dgs[s] = 0.5f * dg;
        }
        __syncthreads();
        s8v ah0 = *(const s8v*)&qnh[(32 * w + lr) * KNROW + lk];
        s8v al0 = *(const s8v*)&qnl[(32 * w + lr) * KNROW + lk];
        s8v ah1 = *(const s8v*)&qnh[(32 * w + 16 + lr) * KNROW + lk];
        s8v al1 = *(const s8v*)&qnl[(32 * w + 16 + lr) * KNROW + lk];
        f4v D0[4], D1[4];
        #pragma unroll
        for (int mt = 0; mt < 4; ++mt) {
            s8v bh = *(const s8v*)&ph[(mt * 16 + lr) * KNROW + lk];
            s8v bl = *(const s8v*)&pl[(mt * 16 + lr) * KNROW + lk];
            f4v d0 = {0.f, 0.f, 0.f, 0.f}, d1 = {0.f, 0.f, 0.f, 0.f};
            d0 = MFMA16(ah0, bh, d0); d0 = MFMA16(ah0, bl, d0); d0 = MFMA16(al0, bh, d0);
            d1 = MFMA16(ah1, bh, d1); d1 = MFMA16(ah1, bl, d1); d1 = MFMA16(al1, bh, d1);
            D0[mt] = d0; D1[mt] = d1;
        }
        f4v dg0 = *(const f4v*)&dgs[32 * w + l4];
        f4v dg1 = *(const f4v*)&dgs[32 * w + 16 + l4];
        // per-row max over real m only (pad lanes of m-tile 3 masked)
        float mx0[4], mx1[4];
        #pragma unroll
        for (int r = 0; r < 4; ++r) {
            float v3 = (lr < NBF - 48) ? D0[3][r] : -3.4e38f;
            float mm = fmaxf(fmaxf(D0[0][r], D0[1][r]), fmaxf(D0[2][r], v3));
            mm = fmaxf(mm, __shfl_xor(mm, 1));
            mm = fmaxf(mm, __shfl_xor(mm, 2));
            mm = fmaxf(mm, __shfl_xor(mm, 4));
            mm = fmaxf(mm, __shfl_xor(mm, 8));
            mx0[r] = mm;
            float u3 = (lr < NBF - 48) ? D1[3][r] : -3.4e38f;
            float nn = fmaxf(fmaxf(D1[0][r], D1[1][r]), fmaxf(D1[2][r], u3));
            nn = fmaxf(nn, __shfl_xor(nn, 1));
            nn = fmaxf(nn, __shfl_xor(nn, 2));
            nn = fmaxf(nn, __shfl_xor(nn, 4));
            nn = fmaxf(nn, __shfl_xor(nn, 8));
            mx1[r] = nn;
        }
        #pragma unroll
        for (int mt = 0; mt < 4; ++mt) {
            int m = mt * 16 + lr;
            bool valid = m < NBF;
            #pragma unroll
            for (int r = 0; r < 4; ++r) {
                float p0 = valid ? RATIO * (__expf(D0[mt][r] - dg0[r] - mx0[r]) + KEPS) : 0.f;
                float p1 = valid ? RATIO * (__expf(D1[mt][r] - dg1[r] - mx1[r]) + KEPS) : 0.f;
                qp[(32 * w + l4 + r) * QPROW + m] = (short)f2u(p0);
                qp[(32 * w + 16 + l4 + r) * QPROW + m] = (short)f2u(p1);
            }
        }
        __syncthreads();
        // out MFMA: wave w owns s-tiles {2w,2w+1} x d-tiles {0,1}, K=64
        f4v o00 = {0.f,0.f,0.f,0.f}, o01 = {0.f,0.f,0.f,0.f};
        f4v o10 = {0.f,0.f,0.f,0.f}, o11 = {0.f,0.f,0.f,0.f};
        #pragma unroll
        for (int ks = 0; ks < 2; ++ks) {
            s8v a0 = *(const s8v*)&qp[(32 * w + lr) * QPROW + ks * 32 + lk];
            s8v a1 = *(const s8v*)&qp[(32 * w + 16 + lr) * QPROW + ks * 32 + lk];
            s8v b0 = *(const s8v*)&cT[lr * QPROW + ks * 32 + lk];
            s8v b1 = *(const s8v*)&cT[(16 + lr) * QPROW + ks * 32 + lk];
            o00 = MFMA16(a0, b0, o00); o01 = MFMA16(a0, b1, o01);
            o10 = MFMA16(a1, b0, o10); o11 = MFMA16(a1, b1, o11);
        }
        int base_col = h * DH;
        #pragma unroll
        for (int r = 0; r < 4; ++r) {
            float den0 = __shfl(o01[r], (l & 48) | 4);   // col d=20 holder
            float den1 = __shfl(o11[r], (l & 48) | 4);
            float di0 = 1.f / den0, di1 = 1.f / den1;
            size_t tok0 = (size_t)n * SEQ + s0 + 32 * w + l4 + r;
            size_t tok1 = tok0 + 16;
            u16* o0p = (u16*)ao + tok0 * DIM + base_col;
            u16* o1p = (u16*)ao + tok1 * DIM + base_col;
            o0p[lr] = f2u(o00[r] * di0);
            if (lr < 4) o0p[16 + lr] = f2u(o01[r] * di0);
            o1p[lr] = f2u(o10[r] * di1);
            if (lr < 4) o1p[16 + lr] = f2u(o11[r] * di1);
        }
    }
}

// ---------------- pooling ----------------
__global__ __launch_bounds__(256) void pool1_kernel(const bf16* __restrict__ hn,
        float* __restrict__ partial) {
    int n = blockIdx.x / 16, c = blockIdx.x % 16;
    int d = threadIdx.x;
    if (d >= DIM) return;
    float acc = 0.f;
    const bf16* base = hn + ((size_t)n * SEQ + c * 128) * DIM + d;
    for (int s = 0; s < 128; ++s) acc += b2f(base[(size_t)s * DIM]);
    partial[(size_t)blockIdx.x * DIM + d] = acc;
}

__global__ __launch_bounds__(256) void pool2_kernel(const float* __restrict__ partial,
        float* __restrict__ pooled) {
    int n = blockIdx.x, d = threadIdx.x;
    if (d >= DIM) return;
    float acc = 0.f;
    for (int c = 0; c < 16; ++c) acc += partial[(size_t)(n * 16 + c) * DIM + d];
    pooled[n * DIM + d] = acc * (1.f / SEQ);
}

__global__ __launch_bounds__(512) void finalproj_kernel(const float* __restrict__ pooled,
        const float* __restrict__ pw, const float* __restrict__ pb,
        float* __restrict__ out) {
    __shared__ float ps[DIM];
    int n = blockIdx.x;
    for (int i = threadIdx.x; i < DIM; i += 512) ps[i] = pooled[n * DIM + i];
    __syncthreads();
    int j = threadIdx.x;
    float acc = pb[j];
    for (int d = 0; d < DIM; ++d) acc += ps[d] * pw[d * DMODEL + j];
    out[n * DMODEL + j] = acc;
}

// ---------------- host launch ----------------
extern "C" void kernel_launch(void* const* d_in, const int* in_sizes, int n_in,
                              void* d_out, int out_size, void* d_ws, size_t ws_size,
                              hipStream_t stream) {
    (void)in_sizes; (void)n_in; (void)out_size;
    const float* x    = (const float*)d_in[0];
    const float* emb  = (const float*)d_in[1];
    const float* ln1g = (const float*)d_in[2];
    const float* ln1b = (const float*)d_in[3];
    const float* wq   = (const float*)d_in[4];
    const float* bq   = (const float*)d_in[5];
    const float* wk   = (const float*)d_in[6];
    const float* bk   = (const float*)d_in[7];
    const float* wv   = (const float*)d_in[8];
    const float* bv   = (const float*)d_in[9];
    const float* proj = (const float*)d_in[10];
    const float* wo   = (const float*)d_in[11];
    const float* bo   = (const float*)d_in[12];
    const float* ln2g = (const float*)d_in[13];
    const float* ln2b = (const float*)d_in[14];
    const float* ffw1 = (const float*)d_in[15];
    const float* ffb1 = (const float*)d_in[16];
    const float* ffw2 = (const float*)d_in[17];
    const float* ffb2 = (const float*)d_in[18];
    const float* lnfg = (const float*)d_in[19];
    const float* lnfb = (const float*)d_in[20];
    const float* pw   = (const float*)d_in[21];
    const float* pb   = (const float*)d_in[22];
    float* out = (float*)d_out;

    const size_t A_ = (size_t)NTOK * DIM;
    bf16* x1 = (bf16*)d_ws;
    bf16* x2 = x1 + A_ + BUFPAD;
    bf16* b3 = x2 + A_ + BUFPAD;     // k -> q ; FF hidden spans b3..b4
    bf16* b4 = b3 + A_ + BUFPAD;     // v -> attn out
    bf16* panel1 = b4 + A_ + BUFPAD;           // [896*224] max
    bf16* panel2 = panel1 + P1ELEM;            // [256*800]
    float* muB   = (float*)(panel2 + P2ELEM);
    float* rstdB = muB + NTOK;
    float* uw    = rstdB + NTOK;               // 3328 floats
    float* ctxg  = uw + 3328;                  // 640 * 21 * 64 floats
    unsigned* kmaxu = (unsigned*)(ctxg + (size_t)NSEQ * HEADS * CTXR * 64);

    float* uq = uw,        *uk = uw + 256,  *uv = uw + 512;
    float* wqf = uw + 768, *wkf = uw + 1024, *wvf = uw + 1280;
    float* u1 = uw + 1536, *w1f = uw + 2432;

    size_t need = (char*)(kmaxu + 16) - (char*)d_ws;
    if (ws_size < need) {
        sentinel_kernel<<<1, 64, 0, stream>>>(out, (float)(ws_size >> 20));
        return;
    }

    zeropad_kernel<<<1, 64, 0, stream>>>(x1 + A_, x2 + A_, b3 + A_, b4 + A_);
    embed_kernel<<<(NTOK * 25 + 255) / 256, 256, 0, stream>>>(x, emb, x1, x2);

    dim3 gqkv(NTOK / 128, 2);
    dim3 gff1(CHROWS / 128, 7);
    dim3 gff2(CHROWS / 128, 2);
    const int PB = 256;
    for (int l = 0; l < DEPTH; ++l) {
        const float* wq_l = wq + (size_t)l * DIM * DIM;
        const float* wk_l = wk + (size_t)l * DIM * DIM;
        const float* wv_l = wv + (size_t)l * DIM * DIM;
        const float* wo_l = wo + (size_t)l * DIM * DIM;
        const float* f1_l = ffw1 + (size_t)l * DIM * FFD;
        const float* f2_l = ffw2 + (size_t)l * FFD * DIM;
        const float* pj_l = proj + (size_t)l * NBF * DH;
        const float* g1 = ln1g + l * DIM, *b1 = ln1b + l * DIM;
        const float* g2 = ln2g + l * DIM, *b2 = ln2b + l * DIM;

        lnstats_kernel<<<NTOK / 4, 256, 0, stream>>>(x2, muB, rstdB);
        prep_uw_qkv<<<3, PB, 0, stream>>>(wq_l, wk_l, wv_l, g1, b1,
                bq + l * DIM, bk + l * DIM, bv + l * DIM, uw);

        // k -> b3
        prep_panel<<<(256 * KPAD + PB - 1) / PB, PB, 0, stream>>>(wk_l, g1, panel1, DIM, DIM, 256, KPAD);
        gemm_m<0, 1><<<gqkv, 256, 0, stream>>>(x2, panel1, wkf, uk, muB, rstdB,
                b3, NTOK, DIM, DIM, KPAD);
        initkmax_kernel<<<1, 64, 0, stream>>>(kmaxu);
        kmax_kernel<<<2048, 256, 0, stream>>>(b3, pj_l, kmaxu);
        // v -> b4
        prep_panel<<<(256 * KPAD + PB - 1) / PB, PB, 0, stream>>>(wv_l, g1, panel1, DIM, DIM, 256, KPAD);
        gemm_m<0, 1><<<gqkv, 256, 0, stream>>>(x2, panel1, wvf, uv, muB, rstdB,
                b4, NTOK, DIM, DIM, KPAD);
        kvctx_mfma<<<NSEQ * HEADS, 256, 0, stream>>>(b3, b4, pj_l, kmaxu, ctxg);
        // q -> b3 (k dead)
        prep_panel<<<(256 * KPAD + PB - 1) / PB, PB, 0, stream>>>(wq_l, g1, panel1, DIM, DIM, 256, KPAD);
        gemm_m<0, 1><<<gqkv, 256, 0, stream>>>(x2, panel1, wqf, uq, muB, rstdB,
                b3, NTOK, DIM, DIM, KPAD);
        // attn out -> b4 (v dead)
        qattn_mfma<<<NSEQ * HEADS, 256, 0, stream>>>(b3, pj_l, ctxg, b4);
        // x1 += b4 @ wo + bo
        prep_panel<<<(256 * KPAD + PB - 1) / PB, PB, 0, stream>>>(wo_l, nullptr, panel1, DIM, DIM, 256, KPAD);
        gemm_m<1, 0><<<gqkv, 256, 0, stream>>>(b4, panel1, bo + l * DIM, nullptr,
                nullptr, nullptr, x1, NTOK, DIM, DIM, KPAD);

        // FF
        lnstats_kernel<<<NTOK / 4, 256, 0, stream>>>(x1, muB, rstdB);
        prep_uw<<<(FFD + PB - 1) / PB, PB, 0, stream>>>(f1_l, g2, b2, ffb1 + l * FFD, u1, w1f, FFD, DIM);
        prep_panel<<<(896 * KPAD + PB - 1) / PB, PB, 0, stream>>>(f1_l, g2, panel1, FFD, DIM, 896, KPAD);
        prep_panel<<<(256 * 800 + PB - 1) / PB, PB, 0, stream>>>(f2_l, nullptr, panel2, DIM, FFD, 256, 800);
        for (int c = 0; c < NCHUNK; ++c) {
            size_t roff = (size_t)c * CHROWS;
            bf16* hid = b3;   // spans b3..b4
            gemm_m<2, 1><<<gff1, 256, 0, stream>>>(x1 + roff * DIM, panel1, w1f, u1,
                    muB + roff, rstdB + roff, hid, CHROWS, FFD, DIM, KPAD);
            gemm_m<1, 0><<<gff2, 256, 0, stream>>>(hid, panel2, ffb2 + l * DIM, nullptr,
                    nullptr, nullptr, x2 + roff * DIM, CHROWS, DIM, FFD, FFD);
        }
    }

    finalln_kernel<<<NTOK / 4, 256, 0, stream>>>(x1, x2, lnfg, lnfb, b3);
    float* partial = muB;
    float* pooled  = muB + (size_t)NSEQ * 16 * DIM;
    pool1_kernel<<<NSEQ * 16, 256, 0, stream>>>(b3, partial);
    pool2_kernel<<<NSEQ, 256, 0, stream>>>(partial, pooled);
    finalproj_kernel<<<NSEQ, 512, 0, stream>>>(pooled, pw, pb, out);
}

// Round 6
// 4999.536 us; speedup vs baseline: 5.2039x; 1.1869x over previous
//
#include <hip/hip_runtime.h>
#include <hip/hip_bf16.h>
#include <math.h>

#define DEPTH   6
#define DIM     200
#define HEADS   10
#define DH      20
#define NBF     59
#define FFD     800
#define DMODEL  512
#define NSEQ    64
#define SEQ     2048
#define NTOK    (NSEQ*SEQ)   // 131072
#define NCHUNK  2
#define CHROWS  (NTOK/NCHUNK)
#define KPAD    224          // ceil(200/32)*32
#define BUFPAD  64
#define KNROW   40           // staged row stride (shorts) for kn/qn/proj
#define VROW    136          // vT row stride
#define KPROW   136          // kp row stride
#define QPROW   72           // qp / ctxT row stride
#define CTXR    21           // ctx rows stored (d=0..19 + ksum row 20)
// panel element counts
#define PKV_E   (512*KPAD)
#define PQ_E    (256*KPAD)
#define PWO_E   (256*KPAD)
#define PF1_E   (896*KPAD)
#define PF2_E   (256*800)

typedef __hip_bfloat16 bf16;
typedef unsigned short u16;
typedef short s8v __attribute__((ext_vector_type(8)));
typedef short s4v __attribute__((ext_vector_type(4)));
typedef float f4v __attribute__((ext_vector_type(4)));

constexpr float SCALE = 0.4728708045015879f;   // 20^-0.25
constexpr float RATIO = 0.1301889109808239f;   // 59^-0.5
constexpr float KEPS  = 1e-4f;

__device__ __forceinline__ float b2f(bf16 v) { return __bfloat162float(v); }
__device__ __forceinline__ bf16 f2b(float v) { return __float2bfloat16(v); }
__device__ __forceinline__ float bfu(u16 u) {
    return __uint_as_float(((unsigned)u) << 16);
}
__device__ __forceinline__ u16 f2u(float v) {
    bf16 hb = __float2bfloat16(v);
    return *(u16*)&hb;
}
__device__ __forceinline__ float gelu_f(float x) {
    return 0.5f * x * (1.f + erff(x * 0.70710678118654752f));
}
#define MFMA16(a, b, c) __builtin_amdgcn_mfma_f32_16x16x32_bf16(a, b, c, 0, 0, 0)

// ---------------- sentinel: encodes ws_size(MB) into out[0] ----------------
__global__ void sentinel_kernel(float* out, float wsmb) {
    if (threadIdx.x == 0) out[0] = wsmb;
}

__global__ void zeropad_kernel(bf16* p1, bf16* p2, bf16* p3, bf16* p4) {
    int i = threadIdx.x;
    if (i < BUFPAD) {
        bf16 z = f2b(0.f);
        p1[i] = z; p2[i] = z; p3[i] = z; p4[i] = z;
    }
}

// ---- per-layer prep: all weight panels (bf16 [N][K] transposed, padded,
// g-folded) + LN-fold vectors u/w, in ONE launch --------------------------
// uw layout (floats): [0..511]=ukv  [512..1023]=wkv  [1024..1279]=uq
// [1280..1535]=wq  [1536..2431]=u1  [2432..3327]=w1
__global__ __launch_bounds__(256) void prep_layer(
        const float* __restrict__ wq, const float* __restrict__ wk,
        const float* __restrict__ wv, const float* __restrict__ wo,
        const float* __restrict__ f1, const float* __restrict__ f2,
        const float* __restrict__ g1, const float* __restrict__ b1,
        const float* __restrict__ g2, const float* __restrict__ b2,
        const float* __restrict__ bq, const float* __restrict__ bk,
        const float* __restrict__ bv, const float* __restrict__ f1b,
        bf16* __restrict__ pKV, bf16* __restrict__ pQ, bf16* __restrict__ pWO,
        bf16* __restrict__ pF1, bf16* __restrict__ pF2,
        float* __restrict__ uw) {
    int b = blockIdx.x, t = threadIdx.x;
    if (b < 448) {                      // pKV: rows 0..255 = k, 256..511 = v
        int idx = b * 256 + t;
        int row = idx / KPAD, k = idx % KPAD;
        float v = 0.f;
        if (k < DIM) {
            if (row < DIM) v = wk[(size_t)k * DIM + row] * g1[k];
            else if (row >= 256 && row < 256 + DIM)
                v = wv[(size_t)k * DIM + (row - 256)] * g1[k];
        }
        pKV[idx] = f2b(v);
    } else if (b < 672) {               // pQ
        int idx = (b - 448) * 256 + t;
        int row = idx / KPAD, k = idx % KPAD;
        float v = (row < DIM && k < DIM) ? wq[(size_t)k * DIM + row] * g1[k] : 0.f;
        pQ[idx] = f2b(v);
    } else if (b < 896) {               // pWO (no fold)
        int idx = (b - 672) * 256 + t;
        int row = idx / KPAD, k = idx % KPAD;
        float v = (row < DIM && k < DIM) ? wo[(size_t)k * DIM + row] : 0.f;
        pWO[idx] = f2b(v);
    } else if (b < 1680) {              // pF1 (g2-folded)
        int idx = (b - 896) * 256 + t;
        int row = idx / KPAD, k = idx % KPAD;
        float v = (row < FFD && k < DIM) ? f1[(size_t)k * FFD + row] * g2[k] : 0.f;
        pF1[idx] = f2b(v);
    } else if (b < 2480) {              // pF2 [256][800]
        int idx = (b - 1680) * 256 + t;
        int row = idx / 800, k = idx % 800;
        float v = (row < DIM) ? f2[(size_t)k * DIM + row] : 0.f;
        pF2[idx] = f2b(v);
    } else if (b < 2482) {              // u/w for fused KV
        int j = b - 2480;
        const float* W    = j ? wv : wk;
        const float* bias = j ? bv : bk;
        int n = t;
        float su = 0.f, sw = 0.f;
        if (n < DIM) {
            for (int k = 0; k < DIM; ++k) {
                float wvv = W[(size_t)k * DIM + n];
                su += g1[k] * wvv;
                sw += b1[k] * wvv;
            }
            sw += bias[n];
        }
        uw[j * 256 + n] = su;
        uw[512 + j * 256 + n] = sw;
    } else if (b == 2482) {             // u/w for Q
        int n = t;
        float su = 0.f, sw = 0.f;
        if (n < DIM) {
            for (int k = 0; k < DIM; ++k) {
                float wvv = wq[(size_t)k * DIM + n];
                su += g1[k] * wvv;
                sw += b1[k] * wvv;
            }
            sw += bq[n];
        }
        uw[1024 + n] = su;
        uw[1280 + n] = sw;
    } else {                            // u/w for FF1 (896 outputs)
        int n = (b - 2483) * 256 + t;
        if (n < 896) {
            float su = 0.f, sw = 0.f;
            if (n < FFD) {
                for (int k = 0; k < DIM; ++k) {
                    float wvv = f1[(size_t)k * FFD + n];
                    su += g2[k] * wvv;
                    sw += b2[k] * wvv;
                }
                sw += f1b[n];
            }
            uw[1536 + n] = su;
            uw[2432 + n] = sw;
        }
    }
}

// ---------------- embedding: tokens are 1 (x<=0) or 5 (x>0) ----------------
__global__ __launch_bounds__(256) void embed_kernel(const float* __restrict__ x,
        const float* __restrict__ emb, bf16* __restrict__ x1, bf16* __restrict__ x2) {
    int idx = blockIdx.x * 256 + threadIdx.x;      // NTOK*25
    if (idx >= NTOK * 25) return;
    int t = idx / 25, c = idx % 25;
    int row = (x[t] > 0.f) ? 5 : 1;
    const float4* e4 = (const float4*)(emb + row * DIM + c * 8);
    float4 e0 = e4[0], e1 = e4[1];
    s8v o;
    o[0] = (short)f2u(e0.x); o[1] = (short)f2u(e0.y);
    o[2] = (short)f2u(e0.z); o[3] = (short)f2u(e0.w);
    o[4] = (short)f2u(e1.x); o[5] = (short)f2u(e1.y);
    o[6] = (short)f2u(e1.z); o[7] = (short)f2u(e1.w);
    size_t off = (size_t)t * DIM + c * 8;
    *(s8v*)((short*)x1 + off) = o;
    *(s8v*)((short*)x2 + off) = o;
}

// ---------------- LN stats (one wave per token row of 200) ----------------
__global__ __launch_bounds__(256) void lnstats_kernel(const bf16* __restrict__ in,
        float* __restrict__ mu_o, float* __restrict__ rstd_o) {
    int lane = threadIdx.x & 63;
    size_t t = (size_t)blockIdx.x * 4 + (threadIdx.x >> 6);
    const u16* row = (const u16*)in + t * DIM;
    float v0 = 0.f, v1 = 0.f, v2 = 0.f, v3 = 0.f;
    if (lane < 50) {
        ushort4 u4 = ((const ushort4*)row)[lane];
        v0 = bfu(u4.x); v1 = bfu(u4.y); v2 = bfu(u4.z); v3 = bfu(u4.w);
    }
    float s = v0 + v1 + v2 + v3, qq = v0*v0 + v1*v1 + v2*v2 + v3*v3;
    #pragma unroll
    for (int o = 32; o > 0; o >>= 1) { s += __shfl_xor(s, o); qq += __shfl_xor(qq, o); }
    if (lane == 0) {
        float mu = s * (1.f / DIM);
        mu_o[t] = mu;
        rstd_o[t] = rsqrtf(qq * (1.f / DIM) - mu * mu + 1e-5f);
    }
}

__global__ __launch_bounds__(256) void finalln_kernel(const bf16* __restrict__ in1,
        const bf16* __restrict__ in2, const float* __restrict__ g,
        const float* __restrict__ b, bf16* __restrict__ out) {
    int lane = threadIdx.x & 63;
    size_t t = (size_t)blockIdx.x * 4 + (threadIdx.x >> 6);
    const u16* r1 = (const u16*)in1 + t * DIM;
    const u16* r2 = (const u16*)in2 + t * DIM;
    float v0 = 0.f, v1 = 0.f, v2 = 0.f, v3 = 0.f;
    if (lane < 50) {
        ushort4 a4 = ((const ushort4*)r1)[lane];
        ushort4 b4 = ((const ushort4*)r2)[lane];
        v0 = 0.5f * (bfu(a4.x) + bfu(b4.x));
        v1 = 0.5f * (bfu(a4.y) + bfu(b4.y));
        v2 = 0.5f * (bfu(a4.z) + bfu(b4.z));
        v3 = 0.5f * (bfu(a4.w) + bfu(b4.w));
    }
    float s = v0 + v1 + v2 + v3, qq = v0*v0 + v1*v1 + v2*v2 + v3*v3;
    #pragma unroll
    for (int o = 32; o > 0; o >>= 1) { s += __shfl_xor(s, o); qq += __shfl_xor(qq, o); }
    float mu = s * (1.f / DIM);
    float rstd = rsqrtf(qq * (1.f / DIM) - mu * mu + 1e-5f);
    if (lane < 50) {
        float4 g4 = ((const float4*)g)[lane];
        float4 b4f = ((const float4*)b)[lane];
        ushort4 o4;
        o4.x = f2u((v0 - mu) * rstd * g4.x + b4f.x);
        o4.y = f2u((v1 - mu) * rstd * g4.y + b4f.y);
        o4.z = f2u((v2 - mu) * rstd * g4.z + b4f.z);
        o4.w = f2u((v3 - mu) * rstd * g4.w + b4f.w);
        ((ushort4*)((u16*)out + t * DIM))[lane] = o4;
    }
}

// ---------------- MFMA GEMM: C = epi(A @ Bt^T) + LN-epilogue ----------------
// KV=1: N=512 panel, cols 0..255 -> C (k), 256..511 -> C2 (v), cc<200 guard
template<int EPI, int LNE, int KV>
__global__ __launch_bounds__(256) void gemm_m(
        const bf16* __restrict__ A, const bf16* __restrict__ Bt,
        const float* __restrict__ wv_, const float* __restrict__ uv_,
        const float* __restrict__ mu, const float* __restrict__ rstd,
        bf16* __restrict__ C, bf16* __restrict__ C2,
        int M, int N, int K, int Kpad) {
    __shared__ __align__(16) short As[128 * 40];
    __shared__ __align__(16) short Bs[128 * 40];
    int bm = blockIdx.x * 128, bn = blockIdx.y * 128;
    int t = threadIdx.x, l = t & 63, w = t >> 6;
    int wr = (w >> 1) * 64, wc = (w & 1) * 64;
    int lr = l & 15, lk = (l >> 4) * 8;
    f4v acc[4][4];
    #pragma unroll
    for (int i = 0; i < 4; ++i)
        #pragma unroll
        for (int j = 0; j < 4; ++j) acc[i][j] = (f4v){0.f, 0.f, 0.f, 0.f};

    const short* Ash = (const short*)A;
    const short* Bsh = (const short*)Bt;
    s8v pa[2], pb[2];
    #pragma unroll
    for (int i2 = 0; i2 < 2; ++i2) {
        int c = t * 2 + i2;
        int row = c >> 2, ko = (c & 3) * 8;
        pa[i2] = *(const s8v*)(Ash + (size_t)(bm + row) * K + ko);
        pb[i2] = *(const s8v*)(Bsh + (size_t)(bn + row) * Kpad + ko);
    }
    for (int k0 = 0; k0 < Kpad; k0 += 32) {
        __syncthreads();
        #pragma unroll
        for (int i2 = 0; i2 < 2; ++i2) {
            int c = t * 2 + i2;
            int row = c >> 2, ko = (c & 3) * 8;
            *(s8v*)&As[row * 40 + ko] = pa[i2];
            *(s8v*)&Bs[row * 40 + ko] = pb[i2];
        }
        __syncthreads();
        if (k0 + 32 < Kpad) {
            #pragma unroll
            for (int i2 = 0; i2 < 2; ++i2) {
                int c = t * 2 + i2;
                int row = c >> 2, ko = (c & 3) * 8;
                pa[i2] = *(const s8v*)(Ash + (size_t)(bm + row) * K + k0 + 32 + ko);
                pb[i2] = *(const s8v*)(Bsh + (size_t)(bn + row) * Kpad + k0 + 32 + ko);
            }
        }
        s8v a[4], b[4];
        #pragma unroll
        for (int fi = 0; fi < 4; ++fi)
            a[fi] = *(const s8v*)&As[(wr + fi * 16 + lr) * 40 + lk];
        #pragma unroll
        for (int fj = 0; fj < 4; ++fj)
            b[fj] = *(const s8v*)&Bs[(wc + fj * 16 + lr) * 40 + lk];
        #pragma unroll
        for (int fi = 0; fi < 4; ++fi)
            #pragma unroll
            for (int fj = 0; fj < 4; ++fj)
                acc[fi][fj] = MFMA16(a[fi], b[fj], acc[fi][fj]);
    }
    int r0 = (l >> 4) * 4;
    #pragma unroll
    for (int fi = 0; fi < 4; ++fi) {
        int rowb = bm + wr + fi * 16 + r0;
        float sr[4] = {1.f, 1.f, 1.f, 1.f}, tr[4] = {0.f, 0.f, 0.f, 0.f};
        if (LNE) {
            #pragma unroll
            for (int r = 0; r < 4; ++r) {
                sr[r] = rstd[rowb + r];
                tr[r] = mu[rowb + r] * sr[r];
            }
        }
        #pragma unroll
        for (int fj = 0; fj < 4; ++fj) {
            int col = bn + wc + fj * 16 + lr;
            if (KV) {
                int cc = col & 255;
                if (cc < DIM) {
                    bf16* dst = (col < 256) ? C : C2;
                    float ww = wv_[col], uu = uv_[col];
                    #pragma unroll
                    for (int r = 0; r < 4; ++r) {
                        size_t idx = (size_t)(rowb + r) * DIM + cc;
                        float v = sr[r] * acc[fi][fj][r] - tr[r] * uu + ww;
                        dst[idx] = f2b(v);
                    }
                }
            } else if (col < N) {
                float ww = wv_[col];
                float uu = LNE ? uv_[col] : 0.f;
                #pragma unroll
                for (int r = 0; r < 4; ++r) {
                    size_t idx = (size_t)(rowb + r) * N + col;
                    float v = LNE ? (sr[r] * acc[fi][fj][r] - tr[r] * uu + ww)
                                  : (acc[fi][fj][r] + ww);
                    if (EPI == 1) v += b2f(C[idx]);
                    if (EPI == 2) v = gelu_f(v);
                    C[idx] = f2b(v);
                }
            }
        }
    }
}

// ---- MFMA kvctx with ONLINE per-(n,h) max (flash-style) --------------------
// ctxg[nh][d][m], d=0..19 ctx, d=20 ksum; ctx = RATIO*(cd + KEPS*vsum)
__global__ __launch_bounds__(256) void kvctx_mfma(const bf16* __restrict__ k,
        const bf16* __restrict__ v, const float* __restrict__ proj,
        float* __restrict__ ctxg) {
    __shared__ __align__(16) short ph[64 * KNROW];
    __shared__ __align__(16) short pl[64 * KNROW];
    __shared__ __align__(16) short knh[128 * KNROW];
    __shared__ __align__(16) short knl[128 * KNROW];
    __shared__ __align__(16) short vT[32 * VROW];
    __shared__ __align__(16) short kp[64 * KPROW];
    __shared__ __align__(16) float diag[128];
    __shared__ float wmax[4];
    int nh = blockIdx.x, n = nh / HEADS, h = nh % HEADS;
    int t = threadIdx.x, l = t & 63, w = t >> 6;
    int lr = l & 15, lk = (l >> 4) * 8, l4 = (l >> 4) * 4;
    for (int i = t; i < 64 * 32; i += 256) {
        int m = i >> 5, d = i & 31;
        float val = (m < NBF && d < DH) ? proj[m * DH + d] : 0.f;
        u16 hi = f2u(val);
        ph[m * KNROW + d] = (short)hi;
        pl[m * KNROW + d] = (short)f2u(val - bfu(hi));
    }
    for (int i = t; i < 128 * 12; i += 256) {
        int s = i / 12, d = 20 + i % 12;
        knh[s * KNROW + d] = 0; knl[s * KNROW + d] = 0;
    }
    for (int i = t; i < 12 * 128; i += 256) {
        int d = 20 + (i >> 7), s = i & 127;
        vT[d * VROW + s] = (short)((d == 20) ? f2u(1.0f) : 0);
    }
    s8v ones;
    #pragma unroll
    for (int i = 0; i < 8; ++i) ones[i] = (short)f2u(1.0f);
    float Mrun = -3.0e38f;
    f4v cd0 = {0.f,0.f,0.f,0.f}, cd1 = {0.f,0.f,0.f,0.f};
    f4v vs0 = {0.f,0.f,0.f,0.f}, vs1 = {0.f,0.f,0.f,0.f};
    for (int c = 0; c < 16; ++c) {
        int s0 = c * 128;
        __syncthreads();
        if (t < 128) {          // waves 0,1: stage kn hi/lo + diag
            int s = t;
            const u16* kr = (const u16*)k + ((size_t)(n * SEQ + s0 + s)) * DIM + h * DH;
            float dg = 0.f;
            #pragma unroll
            for (int q5 = 0; q5 < 5; ++q5) {
                ushort4 u4 = ((const ushort4*)kr)[q5];
                float f0 = bfu(u4.x) * SCALE, f1 = bfu(u4.y) * SCALE;
                float f2_ = bfu(u4.z) * SCALE, f3 = bfu(u4.w) * SCALE;
                dg += f0*f0 + f1*f1 + f2_*f2_ + f3*f3;
                u16 h0 = f2u(f0), h1 = f2u(f1), h2 = f2u(f2_), h3 = f2u(f3);
                s4v hv = {(short)h0, (short)h1, (short)h2, (short)h3};
                *(s4v*)&knh[s * KNROW + q5 * 4] = hv;
                s4v lv = {(short)f2u(f0 - bfu(h0)), (short)f2u(f1 - bfu(h1)),
                          (short)f2u(f2_ - bfu(h2)), (short)f2u(f3 - bfu(h3))};
                *(s4v*)&knl[s * KNROW + q5 * 4] = lv;
            }
            diag[s] = 0.5f * dg;
        } else {                // waves 2,3: stage vT (scatter to [d][s])
            int s = t - 128;
            const u16* vr = (const u16*)v + ((size_t)(n * SEQ + s0 + s)) * DIM + h * DH;
            #pragma unroll
            for (int q5 = 0; q5 < 5; ++q5) {
                ushort4 u4 = ((const ushort4*)vr)[q5];
                vT[(q5 * 4 + 0) * VROW + s] = (short)u4.x;
                vT[(q5 * 4 + 1) * VROW + s] = (short)u4.y;
                vT[(q5 * 4 + 2) * VROW + s] = (short)u4.z;
                vT[(q5 * 4 + 3) * VROW + s] = (short)u4.w;
            }
        }
        __syncthreads();
        s8v ah0 = *(const s8v*)&knh[(32 * w + lr) * KNROW + lk];
        s8v al0 = *(const s8v*)&knl[(32 * w + lr) * KNROW + lk];
        s8v ah1 = *(const s8v*)&knh[(32 * w + 16 + lr) * KNROW + lk];
        s8v al1 = *(const s8v*)&knl[(32 * w + 16 + lr) * KNROW + lk];
        f4v dg0 = *(const f4v*)&diag[32 * w + l4];
        f4v dg1 = *(const f4v*)&diag[32 * w + 16 + l4];
        f4v D0[4], D1[4];
        #pragma unroll
        for (int mt = 0; mt < 4; ++mt) {
            s8v bh = *(const s8v*)&ph[(mt * 16 + lr) * KNROW + lk];
            s8v bl = *(const s8v*)&pl[(mt * 16 + lr) * KNROW + lk];
            f4v d0 = {0.f, 0.f, 0.f, 0.f}, d1 = {0.f, 0.f, 0.f, 0.f};
            d0 = MFMA16(ah0, bh, d0); d0 = MFMA16(ah0, bl, d0); d0 = MFMA16(al0, bh, d0);
            d1 = MFMA16(ah1, bh, d1); d1 = MFMA16(ah1, bl, d1); d1 = MFMA16(al1, bh, d1);
            D0[mt] = d0; D1[mt] = d1;
        }
        // chunk max over valid m (m = mt*16+lr < 59), full-wave reduce
        float mm = -3.0e38f;
        #pragma unroll
        for (int mt = 0; mt < 4; ++mt) {
            int lim = (mt < 3) ? 16 : (NBF - 48);
            if (lr < lim) {
                #pragma unroll
                for (int r = 0; r < 4; ++r)
                    mm = fmaxf(mm, fmaxf(D0[mt][r], D1[mt][r]));
            }
        }
        #pragma unroll
        for (int o = 32; o > 0; o >>= 1) mm = fmaxf(mm, __shfl_xor(mm, o));
        if (l == 0) wmax[w] = mm;
        __syncthreads();
        float Mnew = fmaxf(fmaxf(wmax[0], wmax[1]), fmaxf(wmax[2], wmax[3]));
        Mnew = fmaxf(Mrun, Mnew);
        float scl = __expf(Mrun - Mnew);
        #pragma unroll
        for (int r = 0; r < 4; ++r) { cd0[r] *= scl; cd1[r] *= scl; }
        Mrun = Mnew;
        #pragma unroll
        for (int mt = 0; mt < 4; ++mt) {
            int m = mt * 16 + lr;
            bool valid = m < NBF;
            s4v o0, o1;
            #pragma unroll
            for (int r = 0; r < 4; ++r) {
                float kp0 = valid ? __expf(D0[mt][r] - dg0[r] - Mnew) : 0.f;
                float kp1 = valid ? __expf(D1[mt][r] - dg1[r] - Mnew) : 0.f;
                o0[r] = (short)f2u(kp0);
                o1[r] = (short)f2u(kp1);
            }
            *(s4v*)&kp[m * KPROW + 32 * w + l4] = o0;
            *(s4v*)&kp[m * KPROW + 32 * w + 16 + l4] = o1;
        }
        __syncthreads();
        // ctx MFMA: wave w owns m-tile w, both d-tiles, K=128; + vsum via ones
        #pragma unroll
        for (int ks = 0; ks < 4; ++ks) {
            s8v a  = *(const s8v*)&kp[(16 * w + lr) * KPROW + ks * 32 + lk];
            s8v b0 = *(const s8v*)&vT[lr * VROW + ks * 32 + lk];
            s8v b1 = *(const s8v*)&vT[(16 + lr) * VROW + ks * 32 + lk];
            cd0 = MFMA16(a, b0, cd0);
            cd1 = MFMA16(a, b1, cd1);
            vs0 = MFMA16(ones, b0, vs0);
            vs1 = MFMA16(ones, b1, vs1);
        }
    }
    float* cg = ctxg + (size_t)nh * CTXR * 64;
    int m0 = 16 * w + l4;
    f4v r0v, r1v;
    #pragma unroll
    for (int r = 0; r < 4; ++r) {
        r0v[r] = RATIO * (cd0[r] + KEPS * vs0[r]);
        r1v[r] = RATIO * (cd1[r] + KEPS * vs1[r]);
    }
    *(f4v*)&cg[lr * 64 + m0] = r0v;
    if (lr < 5) *(f4v*)&cg[(16 + lr) * 64 + m0] = r1v;
}

// ---- MFMA qattn: out = (qp @ ctx) * dinv (den via ksum column) -------------
__global__ __launch_bounds__(256) void qattn_mfma(const bf16* __restrict__ q,
        const float* __restrict__ proj, const float* __restrict__ ctxg,
        bf16* __restrict__ ao) {
    __shared__ __align__(16) short ph[64 * KNROW];
    __shared__ __align__(16) short pl[64 * KNROW];
    __shared__ __align__(16) short qnh[128 * KNROW];
    __shared__ __align__(16) short qnl[128 * KNROW];
    __shared__ __align__(16) short qp[128 * QPROW];
    __shared__ __align__(16) short cT[32 * QPROW];
    __shared__ __align__(16) float dgs[128];
    __shared__ __align__(16) float osf[128][22];
    int b = blockIdx.x;
    int nh = b >> 1, sc = b & 1;
    int n = nh / HEADS, h = nh % HEADS;
    int t = threadIdx.x, l = t & 63, w = t >> 6;
    int lr = l & 15, lk = (l >> 4) * 8, l4 = (l >> 4) * 4;
    for (int i = t; i < 64 * 32; i += 256) {
        int m = i >> 5, d = i & 31;
        float val = (m < NBF && d < DH) ? proj[m * DH + d] : 0.f;
        u16 hi = f2u(val);
        ph[m * KNROW + d] = (short)hi;
        pl[m * KNROW + d] = (short)f2u(val - bfu(hi));
    }
    for (int i = t; i < 128 * 12; i += 256) {
        int s = i / 12, d = 20 + i % 12;
        qnh[s * KNROW + d] = 0; qnl[s * KNROW + d] = 0;
    }
    for (int i = t; i < 32 * 64; i += 256) {
        int d = i >> 6, m = i & 63;
        float val = (d < CTXR) ? ctxg[(size_t)nh * CTXR * 64 + d * 64 + m] : 0.f;
        cT[d * QPROW + m] = (short)f2u(val);
    }
    for (int c = 0; c < 8; ++c) {
        int s0 = (sc * 8 + c) * 128;
        __syncthreads();
        if (t < 128) {
            int s = t;
            const u16* qr = (const u16*)q + ((size_t)(n * SEQ + s0 + s)) * DIM + h * DH;
            float dg = 0.f;
            #pragma unroll
            for (int q5 = 0; q5 < 5; ++q5) {
                ushort4 u4 = ((const ushort4*)qr)[q5];
                float f0 = bfu(u4.x) * SCALE, f1 = bfu(u4.y) * SCALE;
                float f2_ = bfu(u4.z) * SCALE, f3 = bfu(u4.w) * SCALE;
                dg += f0*f0 + f1*f1 + f2_*f2_ + f3*f3;
                u16 h0 = f2u(f0), h1 = f2u(f1), h2 = f2u(f2_), h3 = f2u(f3);
                s4v hv = {(short)h0, (short)h1, (short)h2, (short)h3};
                *(s4v*)&qnh[s * KNROW + q5 * 4] = hv;
                s4v lv = {(short)f2u(f0 - bfu(h0)), (short)f2u(f1 - bfu(h1)),
                          (short)f2u(f2_ - bfu(h2)), (short)f2u(f3 - bfu(h3))};
                *(s4v*)&qnl[s * KNROW + q5 * 4] = lv;
            }
            dgs[s] = 0.5f * dg;
        }
        __syncthreads();
        s8v ah0 = *(const s8v*)&qnh[(32 * w + lr) * KNROW + lk];
        s8v al0 = *(const s8v*)&qnl[(32 * w + lr) * KNROW + lk];
        s8v ah1 = *(const s8v*)&qnh[(32 * w + 16 + lr) * KNROW + lk];
        s8v al1 = *(const s8v*)&qnl[(32 * w + 16 + lr) * KNROW + lk];
        f4v D0[4], D1[4];
        #pragma unroll
        for (int mt = 0; mt < 4; ++mt) {
            s8v bh = *(const s8v*)&ph[(mt * 16 + lr) * KNROW + lk];
            s8v bl = *(const s8v*)&pl[(mt * 16 + lr) * KNROW + lk];
            f4v d0 = {0.f, 0.f, 0.f, 0.f}, d1 = {0.f, 0.f, 0.f, 0.f};
            d0 = MFMA16(ah0, bh, d0); d0 = MFMA16(ah0, bl, d0); d0 = MFMA16(al0, bh, d0);
            d1 = MFMA16(ah1, bh, d1); d1 = MFMA16(ah1, bl, d1); d1 = MFMA16(al1, bh, d1);
            D0[mt] = d0; D1[mt] = d1;
        }
        f4v dg0 = *(const f4v*)&dgs[32 * w + l4];
        f4v dg1 = *(const f4v*)&dgs[32 * w + 16 + l4];
        float mx0[4], mx1[4];
        #pragma unroll
        for (int r = 0; r < 4; ++r) {
            float v3 = (lr < NBF - 48) ? D0[3][r] : -3.4e38f;
            float mm = fmaxf(fmaxf(D0[0][r], D0[1][r]), fmaxf(D0[2][r], v3));
            mm = fmaxf(mm, __shfl_xor(mm, 1));
            mm = fmaxf(mm, __shfl_xor(mm, 2));
            mm = fmaxf(mm, __shfl_xor(mm, 4));
            mm = fmaxf(mm, __shfl_xor(mm, 8));
            mx0[r] = mm;
            float u3 = (lr < NBF - 48) ? D1[3][r] : -3.4e38f;
            float nn = fmaxf(fmaxf(D1[0][r], D1[1][r]), fmaxf(D1[2][r], u3));
            nn = fmaxf(nn, __shfl_xor(nn, 1));
            nn = fmaxf(nn, __shfl_xor(nn, 2));
            nn = fmaxf(nn, __shfl_xor(nn, 4));
            nn = fmaxf(nn, __shfl_xor(nn, 8));
            mx1[r] = nn;
        }
        #pragma unroll
        for (int mt = 0; mt < 4; ++mt) {
            int m = mt * 16 + lr;
            bool valid = m < NBF;
            #pragma unroll
            for (int r = 0; r < 4; ++r) {
                float p0 = valid ? RATIO * (__expf(D0[mt][r] - dg0[r] - mx0[r]) + KEPS) : 0.f;
                float p1 = valid ? RATIO * (__expf(D1[mt][r] - dg1[r] - mx1[r]) + KEPS) : 0.f;
                qp[(32 * w + l4 + r) * QPROW + m] = (short)f2u(p0);
                qp[(32 * w + 16 + l4 + r) * QPROW + m] = (short)f2u(p1);
            }
        }
        __syncthreads();
        f4v o00 = {0.f,0.f,0.f,0.f}, o01 = {0.f,0.f,0.f,0.f};
        f4v o10 = {0.f,0.f,0.f,0.f}, o11 = {0.f,0.f,0.f,0.f};
        #pragma unroll
        for (int ks = 0; ks < 2; ++ks) {
            s8v a0 = *(const s8v*)&qp[(32 * w + lr) * QPROW + ks * 32 + lk];
            s8v a1 = *(const s8v*)&qp[(32 * w + 16 + lr) * QPROW + ks * 32 + lk];
            s8v b0 = *(const s8v*)&cT[lr * QPROW + ks * 32 + lk];
            s8v b1 = *(const s8v*)&cT[(16 + lr) * QPROW + ks * 32 + lk];
            o00 = MFMA16(a0, b0, o00); o01 = MFMA16(a0, b1, o01);
            o10 = MFMA16(a1, b0, o10); o11 = MFMA16(a1, b1, o11);
        }
        // stage outputs (f32) to LDS for coalesced write
        #pragma unroll
        for (int r = 0; r < 4; ++r) {
            osf[32 * w + l4 + r][lr] = o00[r];
            osf[32 * w + 16 + l4 + r][lr] = o10[r];
            if (lr < 5) {
                osf[32 * w + l4 + r][16 + lr] = o01[r];
                osf[32 * w + 16 + l4 + r][16 + lr] = o11[r];
            }
        }
        __syncthreads();
        if (t < 128) osf[t][21] = 1.f / osf[t][20];
        __syncthreads();
        int tokb = n * SEQ + s0;
        for (int idx = t; idx < 128 * 10; idx += 256) {
            int row = idx / 10, seg = idx % 10;
            float di = osf[row][21];
            ushort2 o2;
            o2.x = f2u(osf[row][seg * 2] * di);
            o2.y = f2u(osf[row][seg * 2 + 1] * di);
            *(ushort2*)((u16*)ao + (size_t)(tokb + row) * DIM + h * DH + seg * 2) = o2;
        }
    }
}

// ---------------- pooling ----------------
__global__ __launch_bounds__(256) void pool1_kernel(const bf16* __restrict__ hn,
        float* __restrict__ partial) {
    int n = blockIdx.x / 16, c = blockIdx.x % 16;
    int d = threadIdx.x;
    if (d >= DIM) return;
    float acc = 0.f;
    const bf16* base = hn + ((size_t)n * SEQ + c * 128) * DIM + d;
    for (int s = 0; s < 128; ++s) acc += b2f(base[(size_t)s * DIM]);
    partial[(size_t)blockIdx.x * DIM + d] = acc;
}

__global__ __launch_bounds__(256) void pool2_kernel(const float* __restrict__ partial,
        float* __restrict__ pooled) {
    int n = blockIdx.x, d = threadIdx.x;
    if (d >= DIM) return;
    float acc = 0.f;
    for (int c = 0; c < 16; ++c) acc += partial[(size_t)(n * 16 + c) * DIM + d];
    pooled[n * DIM + d] = acc * (1.f / SEQ);
}

__global__ __launch_bounds__(512) void finalproj_kernel(const float* __restrict__ pooled,
        const float* __restrict__ pw, const float* __restrict__ pb,
        float* __restrict__ out) {
    __shared__ float ps[DIM];
    int n = blockIdx.x;
    for (int i = threadIdx.x; i < DIM; i += 512) ps[i] = pooled[n * DIM + i];
    __syncthreads();
    int j = threadIdx.x;
    float acc = pb[j];
    for (int d = 0; d < DIM; ++d) acc += ps[d] * pw[d * DMODEL + j];
    out[n * DMODEL + j] = acc;
}

// ---------------- host launch ----------------
extern "C" void kernel_launch(void* const* d_in, const int* in_sizes, int n_in,
                              void* d_out, int out_size, void* d_ws, size_t ws_size,
                              hipStream_t stream) {
    (void)in_sizes; (void)n_in; (void)out_size;
    const float* x    = (const float*)d_in[0];
    const float* emb  = (const float*)d_in[1];
    const float* ln1g = (const float*)d_in[2];
    const float* ln1b = (const float*)d_in[3];
    const float* wq   = (const float*)d_in[4];
    const float* bq   = (const float*)d_in[5];
    const float* wk   = (const float*)d_in[6];
    const float* bk   = (const float*)d_in[7];
    const float* wv   = (const float*)d_in[8];
    const float* bv   = (const float*)d_in[9];
    const float* proj = (const float*)d_in[10];
    const float* wo   = (const float*)d_in[11];
    const float* bo   = (const float*)d_in[12];
    const float* ln2g = (const float*)d_in[13];
    const float* ln2b = (const float*)d_in[14];
    const float* ffw1 = (const float*)d_in[15];
    const float* ffb1 = (const float*)d_in[16];
    const float* ffw2 = (const float*)d_in[17];
    const float* ffb2 = (const float*)d_in[18];
    const float* lnfg = (const float*)d_in[19];
    const float* lnfb = (const float*)d_in[20];
    const float* pw   = (const float*)d_in[21];
    const float* pb   = (const float*)d_in[22];
    float* out = (float*)d_out;

    const size_t A_ = (size_t)NTOK * DIM;
    bf16* x1 = (bf16*)d_ws;
    bf16* x2 = x1 + A_ + BUFPAD;
    bf16* b3 = x2 + A_ + BUFPAD;     // k -> q ; FF hidden spans b3..b4
    bf16* b4 = b3 + A_ + BUFPAD;     // v -> attn out
    bf16* pKV = b4 + A_ + BUFPAD;
    bf16* pQ  = pKV + PKV_E;
    bf16* pWO = pQ + PQ_E;
    bf16* pF1 = pWO + PWO_E;
    bf16* pF2 = pF1 + PF1_E;
    float* muB   = (float*)(pF2 + PF2_E);
    float* rstdB = muB + NTOK;
    float* uw    = rstdB + NTOK;               // 3328 floats
    float* ctxg  = uw + 3328;                  // 640 * 21 * 64 floats
    float* wsend = ctxg + (size_t)NSEQ * HEADS * CTXR * 64;

    float* ukv = uw,        *wkv = uw + 512;
    float* uq  = uw + 1024, *wqf = uw + 1280;
    float* u1  = uw + 1536, *w1f = uw + 2432;

    size_t need = (char*)wsend - (char*)d_ws;
    if (ws_size < need) {
        sentinel_kernel<<<1, 64, 0, stream>>>(out, (float)(ws_size >> 20));
        return;
    }

    zeropad_kernel<<<1, 64, 0, stream>>>(x1 + A_, x2 + A_, b3 + A_, b4 + A_);
    embed_kernel<<<(NTOK * 25 + 255) / 256, 256, 0, stream>>>(x, emb, x1, x2);

    dim3 gkv(NTOK / 128, 4);
    dim3 gd(NTOK / 128, 2);
    dim3 gff1(CHROWS / 128, 7);
    dim3 gff2(CHROWS / 128, 2);
    for (int l = 0; l < DEPTH; ++l) {
        const float* wq_l = wq + (size_t)l * DIM * DIM;
        const float* wk_l = wk + (size_t)l * DIM * DIM;
        const float* wv_l = wv + (size_t)l * DIM * DIM;
        const float* wo_l = wo + (size_t)l * DIM * DIM;
        const float* f1_l = ffw1 + (size_t)l * DIM * FFD;
        const float* f2_l = ffw2 + (size_t)l * FFD * DIM;
        const float* pj_l = proj + (size_t)l * NBF * DH;
        const float* g1 = ln1g + l * DIM, *b1 = ln1b + l * DIM;
        const float* g2 = ln2g + l * DIM, *b2 = ln2b + l * DIM;

        lnstats_kernel<<<NTOK / 4, 256, 0, stream>>>(x2, muB, rstdB);
        prep_layer<<<2487, 256, 0, stream>>>(wq_l, wk_l, wv_l, wo_l, f1_l, f2_l,
                g1, b1, g2, b2, bq + l * DIM, bk + l * DIM, bv + l * DIM,
                ffb1 + l * FFD, pKV, pQ, pWO, pF1, pF2, uw);

        // k -> b3, v -> b4 (fused)
        gemm_m<0, 1, 1><<<gkv, 256, 0, stream>>>(x2, pKV, wkv, ukv, muB, rstdB,
                b3, b4, NTOK, 512, DIM, KPAD);
        kvctx_mfma<<<NSEQ * HEADS, 256, 0, stream>>>(b3, b4, pj_l, ctxg);
        // q -> b3 (k dead)
        gemm_m<0, 1, 0><<<gd, 256, 0, stream>>>(x2, pQ, wqf, uq, muB, rstdB,
                b3, nullptr, NTOK, DIM, DIM, KPAD);
        // attn out -> b4 (v dead)
        qattn_mfma<<<NSEQ * HEADS * 2, 256, 0, stream>>>(b3, pj_l, ctxg, b4);
        // x1 += b4 @ wo + bo
        gemm_m<1, 0, 0><<<gd, 256, 0, stream>>>(b4, pWO, bo + l * DIM, nullptr,
                nullptr, nullptr, x1, nullptr, NTOK, DIM, DIM, KPAD);

        // FF
        lnstats_kernel<<<NTOK / 4, 256, 0, stream>>>(x1, muB, rstdB);
        for (int c = 0; c < NCHUNK; ++c) {
            size_t roff = (size_t)c * CHROWS;
            bf16* hid = b3;   // spans b3..b4
            gemm_m<2, 1, 0><<<gff1, 256, 0, stream>>>(x1 + roff * DIM, pF1, w1f, u1,
                    muB + roff, rstdB + roff, hid, nullptr, CHROWS, FFD, DIM, KPAD);
            gemm_m<1, 0, 0><<<gff2, 256, 0, stream>>>(hid, pF2, ffb2 + l * DIM, nullptr,
                    nullptr, nullptr, x2 + roff * DIM, nullptr, CHROWS, DIM, FFD, FFD);
        }
    }

    finalln_kernel<<<NTOK / 4, 256, 0, stream>>>(x1, x2, lnfg, lnfb, b3);
    float* partial = muB;
    float* pooled  = muB + (size_t)NSEQ * 16 * DIM;
    pool1_kernel<<<NSEQ * 16, 256, 0, stream>>>(b3, partial);
    pool2_kernel<<<NSEQ, 256, 0, stream>>>(partial, pooled);
    finalproj_kernel<<<NSEQ, 512, 0, stream>>>(pooled, pw, pb, out);
}